// Round 1
// baseline (694.870 us; speedup 1.0000x reference)
//
#include <hip/hip_runtime.h>

#define BEVW 432
#define BEVH 496
#define NCELL (BEVW*BEVH)      // 214272
#define NVOX  40000
#define EPSB  1e-5f

typedef float f32x2 __attribute__((ext_vector_type(2)));
typedef float f32x4 __attribute__((ext_vector_type(4)));
typedef unsigned int u32x4 __attribute__((ext_vector_type(4)));
typedef short bf16x8 __attribute__((ext_vector_type(8)));

// ---- repeat macros ----
#define REP8_0(M)  M(0) M(1) M(2) M(3) M(4) M(5) M(6) M(7)
#define REP8_8(M)  M(8) M(9) M(10) M(11) M(12) M(13) M(14) M(15)
#define REP8_16(M) M(16) M(17) M(18) M(19) M(20) M(21) M(22) M(23)
#define REP8_24(M) M(24) M(25) M(26) M(27) M(28) M(29) M(30) M(31)
#define REP16_0(M)  REP8_0(M)  REP8_8(M)
#define REP32_0(M) REP16_0(M) REP8_16(M) REP8_24(M)

// ---------------- workspace layout (bytes) ----------------
// 0        : int nact (zeroed)
// 256      : int cnt[NCELL]  (zeroed)            -> 857344
// 857344   : int idx[NCELL]  (zeroed; aidx+1)    -> 1714432
// 1714432  : int list[NCELL*16]                  -> 15427840
// 15427840 : float voxelwise[NVOX*64]            -> 25667840
// 25667840 : int act[NVOX]                       -> 25827840
// 25827840 : float x17g[NVOX*128] (x17 then x19) -> 46307840
// 46307840 : float fold[1168]
// 46312512 : ushort w4fh[4096] | 46320704: w4fl | 46337088... w3fh@46328896 w3fl@46337088

__device__ __forceinline__ float mishf(float y) {
    float e = __expf(fminf(y, 40.f));
    float n = e * (e + 2.f);
    return y * n * __builtin_amdgcn_rcpf(n + 2.f);
}

template <int CTRL>
__device__ __forceinline__ float dppmaxf(float a) {
    int p = __builtin_amdgcn_update_dpp(0, __float_as_int(a), CTRL, 0xF, 0xF, true);
    return fmaxf(a, __int_as_float(p));
}
#define WMAX32(a) { \
    a = dppmaxf<0xB1>(a); \
    a = dppmaxf<0x4E>(a); \
    a = dppmaxf<0x141>(a); \
    a = dppmaxf<0x140>(a); \
    a = fmaxf(a, __int_as_float(__builtin_amdgcn_ds_swizzle(__float_as_int(a), 0x401F))); }

__device__ __forceinline__ bf16x8 mkbf8(uint a, uint b, uint c, uint d) {
    u32x4 t = {a, b, c, d};
    return __builtin_bit_cast(bf16x8, t);
}

// split fp32 -> (hi bf16 | lo bf16 << 16). Hi = TRUNCATION (1 op); lo = x - hi is
// then exact in fp32, RNE'd to bf16. Combined representation err ~2^-17 rel.
__device__ __forceinline__ uint splitbf(float x) {
    uint rh = __float_as_uint(x) & 0xFFFF0000u;
    float lof = x - __uint_as_float(rh);
    uint ul = __float_as_uint(lof);
    uint rl = (ul + 0x7FFFu + ((ul >> 16) & 1u)) >> 16;
    return (rh >> 16) | (rl << 16);
}

// fold layout: vfe1 s@0 t@8 | vfe2 s@16 t@48 | vfe3 s@80 t@144 | vfe4 s@208 t@272
// bfe3 s@336 t@464 | bfe1 s@592 t@848 | bfe2 s@1104 t@1136
__global__ __launch_bounds__(256) void setup_kernel(
    const float* __restrict__ vbn1, const float* __restrict__ vbn2,
    const float* __restrict__ vbn3, const float* __restrict__ vbn4,
    const float* __restrict__ bbn1, const float* __restrict__ bbn2,
    const float* __restrict__ bbn3, const float* __restrict__ W4,
    const float* __restrict__ W3g,
    float* __restrict__ fold, ushort* __restrict__ w4fh, ushort* __restrict__ w4fl,
    ushort* __restrict__ w3fh, ushort* __restrict__ w3fl)
{
    int tid = threadIdx.x;
    if (tid < 8)  { float s = vbn1[tid]/sqrtf(vbn1[24+tid]+EPSB);  fold[tid]      = s; fold[8+tid]   = vbn1[8+tid]  - vbn1[16+tid]*s; }
    if (tid < 32) { float s = vbn2[tid]/sqrtf(vbn2[96+tid]+EPSB);  fold[16+tid]   = s; fold[48+tid]  = vbn2[32+tid] - vbn2[64+tid]*s; }
    if (tid < 64) { float s = vbn3[tid]/sqrtf(vbn3[192+tid]+EPSB); fold[80+tid]   = s; fold[144+tid] = vbn3[64+tid] - vbn3[128+tid]*s; }
    if (tid < 64) { float s = vbn4[tid]/sqrtf(vbn4[192+tid]+EPSB); fold[208+tid]  = s; fold[272+tid] = vbn4[64+tid] - vbn4[128+tid]*s; }
    if (tid < 128){ float s = bbn3[tid]/sqrtf(bbn3[384+tid]+EPSB); fold[336+tid]  = s; fold[464+tid] = bbn3[128+tid]- bbn3[256+tid]*s; }
    { int g = tid >> 4, q = tid & 15;
      const float* b = bbn1 + g*64;
      float s = b[q]/sqrtf(b[48+q]+EPSB);
      fold[592+tid] = s; fold[848+tid] = b[16+q] - b[32+q]*s; }
    if (tid < 32) { int g = tid >> 1, c = tid & 1;
      const float* b = bbn2 + g*8;
      float s = b[c]/sqrtf(b[6+c]+EPSB);
      fold[1104+tid] = s; fold[1136+tid] = b[2+c] - b[4+c]*s; }

    // B-fragments (B[k][n] = W[n][k]) split bf16 hi/lo, for W4^T and W3^T.
    // frag idx = ((kc*4 + nt)*64 + lane)*8 + j ; n = (lane&15)+16nt ; k = kc*32 + (lane>>4)*8 + j
    for (int i = tid; i < 4096; i += 256) {
        int j = i & 7, ln = (i >> 3) & 63, nt = (i >> 9) & 3, kc = i >> 11;
        int n = (ln & 15) + nt*16;
        int k = kc*32 + (ln >> 4)*8 + j;
        {
            float val = W4[n*64 + k];
            uint rh = __float_as_uint(val) & 0xFFFF0000u;
            float lof = val - __uint_as_float(rh);
            uint ul = __float_as_uint(lof);
            uint rl = (ul + 0x7FFFu + ((ul >> 16) & 1u)) >> 16;
            w4fh[i] = (ushort)(rh >> 16);
            w4fl[i] = (ushort)rl;
        }
        {
            float val = W3g[n*64 + k];
            uint rh = __float_as_uint(val) & 0xFFFF0000u;
            float lof = val - __uint_as_float(rh);
            uint ul = __float_as_uint(lof);
            uint rl = (ul + 0x7FFFu + ((ul >> 16) & 1u)) >> 16;
            w3fh[i] = (ushort)(rh >> 16);
            w3fl[i] = (ushort)rl;
        }
    }
}

// pair lists
#define PAIRS8(M) M(0,0,1) M(1,2,3) M(2,4,5) M(3,6,7) M(4,8,9) M(5,10,11) \
  M(6,12,13) M(7,14,15)

#define MF3(D, AH, AL, BH, BL) \
    D = __builtin_amdgcn_mfma_f32_16x16x32_bf16(AL, BH, D, 0, 0, 0); \
    D = __builtin_amdgcn_mfma_f32_16x16x32_bf16(AH, BL, D, 0, 0, 0); \
    D = __builtin_amdgcn_mfma_f32_16x16x32_bf16(AH, BH, D, 0, 0, 0);

// A-tile group: A frags from LDS rows (stride 33), 4 B frags from L1, 12 MFMAs.
#define DOMTX(SRCP, BHP, BLP, mt, D0, D1, D2, D3) { \
    const uint* ap_ = (SRCP) + ((lane & 15) + 16*(mt))*33 + quad*8; \
    uint u0 = ap_[0], u1 = ap_[1], u2 = ap_[2], u3 = ap_[3]; \
    uint u4 = ap_[4], u5 = ap_[5], u6 = ap_[6], u7 = ap_[7]; \
    bf16x8 Ah = mkbf8(__builtin_amdgcn_perm(u1,u0,0x05040100), __builtin_amdgcn_perm(u3,u2,0x05040100), \
                      __builtin_amdgcn_perm(u5,u4,0x05040100), __builtin_amdgcn_perm(u7,u6,0x05040100)); \
    bf16x8 Al = mkbf8(__builtin_amdgcn_perm(u1,u0,0x07060302), __builtin_amdgcn_perm(u3,u2,0x07060302), \
                      __builtin_amdgcn_perm(u5,u4,0x07060302), __builtin_amdgcn_perm(u7,u6,0x07060302)); \
    { uint4 h = (BHP)[0];   uint4 l = (BLP)[0];   bf16x8 Bh = mkbf8(h.x,h.y,h.z,h.w), Bl = mkbf8(l.x,l.y,l.z,l.w); MF3(D0, Ah, Al, Bh, Bl) } \
    { uint4 h = (BHP)[64];  uint4 l = (BLP)[64];  bf16x8 Bh = mkbf8(h.x,h.y,h.z,h.w), Bl = mkbf8(l.x,l.y,l.z,l.w); MF3(D1, Ah, Al, Bh, Bl) } \
    { uint4 h = (BHP)[128]; uint4 l = (BLP)[128]; bf16x8 Bh = mkbf8(h.x,h.y,h.z,h.w), Bl = mkbf8(l.x,l.y,l.z,l.w); MF3(D2, Ah, Al, Bh, Bl) } \
    { uint4 h = (BHP)[192]; uint4 l = (BLP)[192]; bf16x8 Bh = mkbf8(h.x,h.y,h.z,h.w), Bl = mkbf8(l.x,l.y,l.z,l.w); MF3(D3, Ah, Al, Bh, Bl) } }

// ---------------- VFE: single-wave blocks, ONE voxel per wave ----------------
// 64 lanes = 32 points x 2 channel-halves (lane = t + 32*h; half h owns fe2
// channels h*16..h*16+15). fe1 (8ch, tiny) is duplicated in both halves so no
// cross-half exchange is needed. WMAX32's DPP+swizzle chain reduces within
// 32-lane halves, which is exactly the per-voxel point set.
// LDS = 2 chunks x 32 rows x 33 u32 = 8448 B (fp32 agg lives in chunk0's pad
// column), halving the 17 KiB 2-voxel layout -> LDS cap 18 blocks/CU vs 9.
// Accumulators halve too (8+8 f32x4), so (64,4) = 128-reg budget fits;
// occupancy target ~16 waves/CU (was 9).
__global__ __launch_bounds__(64, 4) void vfe_kernel(
    const float* __restrict__ feat, const int* __restrict__ coors,
    const int* __restrict__ nvx,
    const float* __restrict__ W1, const float* __restrict__ W2,
    const ushort* __restrict__ w3fh, const ushort* __restrict__ w3fl,
    const ushort* __restrict__ w4fh, const ushort* __restrict__ w4fl,
    const float* __restrict__ fold,
    float* __restrict__ voxelwise, int* __restrict__ cnt,
    int* __restrict__ list, int* __restrict__ nact, int* __restrict__ act)
{
    __shared__ char ldsbuf[8448];   // x2s[2][32][33] u32 ; agg fp32 in chunk0 pad col
    int tid = threadIdx.x;
    int lane = tid;
    int quad = lane >> 4;
    int v = blockIdx.x;
    int t = tid & 31;
    int ho = (tid >> 5) << 4;       // channel-half offset: 0 or 16
    uint*  x2s = (uint*)ldsbuf;
    float* x2f = (float*)ldsbuf;

    const float* fp = feat + (v*32 + t)*8;
    float4 fa = *(const float4*)fp;
    float4 fb = *(const float4*)(fp+4);
    int numv = nvx[v];
    float maskf = (t < numv) ? 1.f : 0.f;

    // ---- fe1 (8->8) + pool (duplicated in both halves) ----
#define D1(o) float x1_##o; float m1_##o;
    REP8_0(D1)
#undef D1
#define FE1(o) { const float* w = W1 + (o)*8; \
    float ya = fa.x*w[0] + fa.y*w[1]; float yb = fa.z*w[2] + fa.w*w[3]; \
    float yc = fb.x*w[4] + fb.y*w[5]; float yd = fb.z*w[6] + fb.w*w[7]; \
    float yy = ((ya+yb)+(yc+yd)) * fold[(o)] + fold[8+(o)]; \
    x1_##o = mishf(yy); }
    REP8_0(FE1)
#undef FE1
#define P1(o) { float a = x1_##o; WMAX32(a); m1_##o = a; }
    REP8_0(P1)
#undef P1

    f32x2 x1p_0 = {x1_0,x1_1}, x1p_1 = {x1_2,x1_3}, x1p_2 = {x1_4,x1_5}, x1p_3 = {x1_6,x1_7};
    f32x2 m1p_0 = {m1_0,m1_1}, m1p_1 = {m1_2,m1_3}, m1p_2 = {m1_4,m1_5}, m1p_3 = {m1_6,m1_7};

    // ---- fe2 (16->16 per half; channel c = ho + o) + pool ----
#define D2(o) float x2_##o; float agg_##o;
    REP16_0(D2)
#undef D2
#define FE2(o) { const f32x2* wp = (const f32x2*)(W2 + (ho + (o))*16); \
    f32x2 sa = x1p_0*wp[0]; sa += x1p_1*wp[1]; \
    f32x2 sb = x1p_2*wp[2]; sb += x1p_3*wp[3]; \
    f32x2 sc = m1p_0*wp[4]; sc += m1p_1*wp[5]; \
    f32x2 sd = m1p_2*wp[6]; sd += m1p_3*wp[7]; \
    sa += sb; sc += sd; sa += sc; \
    float yy = (sa.x + sa.y) * fold[16 + ho + (o)] + fold[48 + ho + (o)]; \
    x2_##o = mishf(yy); }
    REP16_0(FE2)
#undef FE2
#define P2(o) { float a = x2_##o; WMAX32(a); agg_##o = a; }
    REP16_0(P2)
#undef P2

#define PX(i,a,b) f32x2 x2p_##i = {x2_##a, x2_##b}; f32x2 aggp_##i = {agg_##a, agg_##b};
    PAIRS8(PX)
#undef PX

    f32x2 maskp = {maskf, maskf};
#define MSK(i) x2p_##i *= maskp; aggp_##i *= maskp;
    REP8_0(MSK)
#undef MSK

    // exact fp32 agg into chunk0's pad column (lane t==0 always valid -> masked == unmasked)
    if (t == 0) {
#define AGW(i) x2f[(ho + 2*(i))*33 + 32] = aggp_##i.x; x2f[(ho + 2*(i)+1)*33 + 32] = aggp_##i.y;
        REP8_0(AGW)
#undef AGW
    }

    // ---- stage masked x2 split into LDS: chunk0 = fe2-out ch, chunk1 = agg ch ----
#define X2W(i) { \
    x2s[t*33 + ho + 2*(i)]          = splitbf(x2p_##i.x); \
    x2s[t*33 + ho + 2*(i)+1]        = splitbf(x2p_##i.y); \
    x2s[1056 + t*33 + ho + 2*(i)]   = splitbf(aggp_##i.x); \
    x2s[1056 + t*33 + ho + 2*(i)+1] = splitbf(aggp_##i.y); }
    REP8_0(X2W)
#undef X2W

    // ---- fe3: 48 MFMAs over K=64 (2 chunks), M=32 ----
#define E_DECL(i) f32x4 e_##i = {0.f,0.f,0.f,0.f};
    REP8_0(E_DECL)
#undef E_DECL
    {
        const uint4* bh3 = (const uint4*)w3fh + lane;
        const uint4* bl3 = (const uint4*)w3fl + lane;
        DOMTX(x2s, bh3, bl3, 0, e_0, e_1, e_2, e_3)
        DOMTX(x2s, bh3, bl3, 1, e_4, e_5, e_6, e_7)
    }
    {
        const uint4* bh3 = (const uint4*)w3fh + 256 + lane;
        const uint4* bl3 = (const uint4*)w3fl + 256 + lane;
        const uint* sp = x2s + 1056;
        DOMTX(sp, bh3, bl3, 0, e_0, e_1, e_2, e_3)
        DOMTX(sp, bh3, bl3, 1, e_4, e_5, e_6, e_7)
    }

    // ---- fe3 epilogue (bn+mish+split, C-layout) interleaved with fe4 MFMA ----
    int c0 = lane & 15;
    uint* x3st = x2s + 1056;   // agg chunk reused as x3 staging (in-order DS per wave)
#define DD(i) f32x4 d_##i = {0.f,0.f,0.f,0.f};
    REP8_0(DD)
#undef DD

#define POST(TI, mt, nt) { \
    float s_ = fold[80 + c0 + 16*(nt)], tb_ = fold[144 + c0 + 16*(nt)]; \
    int col_ = c0 + 16*((nt)&1); \
    int rowb_ = quad*4 + 16*(mt); \
    x3st[(rowb_+0)*33 + col_] = splitbf(mishf(e_##TI.x * s_ + tb_)); \
    x3st[(rowb_+1)*33 + col_] = splitbf(mishf(e_##TI.y * s_ + tb_)); \
    x3st[(rowb_+2)*33 + col_] = splitbf(mishf(e_##TI.z * s_ + tb_)); \
    x3st[(rowb_+3)*33 + col_] = splitbf(mishf(e_##TI.w * s_ + tb_)); }

    { // staging pass 1: fe3 outputs 0..31 (nt 0,1) -> fe4 kc=0
        POST(0,0,0)  POST(1,0,1)
        POST(4,1,0)  POST(5,1,1)
        const uint4* bh4 = (const uint4*)w4fh + lane;
        const uint4* bl4 = (const uint4*)w4fl + lane;
        DOMTX(x3st, bh4, bl4, 0, d_0, d_1, d_2, d_3)
        DOMTX(x3st, bh4, bl4, 1, d_4, d_5, d_6, d_7)
    }
    { // staging pass 2: fe3 outputs 32..63 (nt 2,3) -> fe4 kc=1
        POST(2,0,2)  POST(3,0,3)
        POST(6,1,2)  POST(7,1,3)
        const uint4* bh4 = (const uint4*)w4fh + 256 + lane;
        const uint4* bl4 = (const uint4*)w4fl + 256 + lane;
        DOMTX(x3st, bh4, bl4, 0, d_0, d_1, d_2, d_3)
        DOMTX(x3st, bh4, bl4, 1, d_4, d_5, d_6, d_7)
    }
#undef POST

    // ---- bn4 + mish + residual + pool in C layout ----
    float s0f = fold[208+c0],    t0f = fold[272+c0];
    float s1f = fold[208+16+c0], t1f = fold[272+16+c0];
    float s2f = fold[208+32+c0], t2f = fold[272+32+c0];
    float s3f = fold[208+48+c0], t3f = fold[272+48+c0];
    float r2 = x2f[c0*33 + 32], r3 = x2f[(16+c0)*33 + 32];
    float p0=-3.4e38f, p1=-3.4e38f, p2=-3.4e38f, p3=-3.4e38f;

#define RECON(u) (__uint_as_float((u)<<16) + __uint_as_float((u) & 0xFFFF0000u))
#define FTP(D, mt, nt, SS, TT, PV) { \
    int rt = quad*4 + 16*(mt); \
    int cb = c0 + 16*(nt); \
    float m0=(rt+0<numv)?1.f:0.f, m1=(rt+1<numv)?1.f:0.f, m2=(rt+2<numv)?1.f:0.f, m3=(rt+3<numv)?1.f:0.f; \
    uint ua_ = x2s[(rt+0)*33 + cb], ub_ = x2s[(rt+1)*33 + cb]; \
    uint uc_ = x2s[(rt+2)*33 + cb], ud_ = x2s[(rt+3)*33 + cb]; \
    float y0 = mishf(D.x*SS + TT)*m0 + RECON(ua_); \
    float y1 = mishf(D.y*SS + TT)*m1 + RECON(ub_); \
    float y2 = mishf(D.z*SS + TT)*m2 + RECON(uc_); \
    float y3 = mishf(D.w*SS + TT)*m3 + RECON(ud_); \
    PV = fmaxf(PV, fmaxf(fmaxf(y0,y1), fmaxf(y2,y3))); }

#define FTA(D, mt, nt, SS, TT, AG, PV) { \
    int rt = quad*4 + 16*(mt); \
    float m0=(rt+0<numv)?1.f:0.f, m1=(rt+1<numv)?1.f:0.f, m2=(rt+2<numv)?1.f:0.f, m3=(rt+3<numv)?1.f:0.f; \
    float y0 = (mishf(D.x*SS + TT) + AG)*m0; \
    float y1 = (mishf(D.y*SS + TT) + AG)*m1; \
    float y2 = (mishf(D.z*SS + TT) + AG)*m2; \
    float y3 = (mishf(D.w*SS + TT) + AG)*m3; \
    PV = fmaxf(PV, fmaxf(fmaxf(y0,y1), fmaxf(y2,y3))); }

    FTP(d_0, 0, 0, s0f, t0f, p0)  FTP(d_1, 0, 1, s1f, t1f, p1)
    FTA(d_2, 0, 2, s2f, t2f, r2, p2)  FTA(d_3, 0, 3, s3f, t3f, r3, p3)
    FTP(d_4, 1, 0, s0f, t0f, p0)  FTP(d_5, 1, 1, s1f, t1f, p1)
    FTA(d_6, 1, 2, s2f, t2f, r2, p2)  FTA(d_7, 1, 3, s3f, t3f, r3, p3)
#undef FTP
#undef FTA
#undef RECON

#define RED(p) p = fmaxf(p, __shfl_xor(p, 16)); p = fmaxf(p, __shfl_xor(p, 32));
    RED(p0) RED(p1) RED(p2) RED(p3)
#undef RED

    if (quad == 0) {
        float* vw = voxelwise + v*64;
        vw[c0] = p0; vw[c0+16] = p1; vw[c0+32] = p2; vw[c0+48] = p3;
    }

    if (lane == 0) {
        int cell = coors[v*2] * BEVW + coors[v*2+1];
        int pos = atomicAdd(&cnt[cell], 1);
        if (pos < 16) list[cell*16 + pos] = v;
        if (pos == 0) { int k = atomicAdd(nact, 1); act[k] = cell; }
    }
}

// ---------------- BFE front: 1 wave = 1 cell; records idx[cell]=aidx+1 ----------------
__global__ __launch_bounds__(256) void bfe_front(
    const int* __restrict__ nact, const int* __restrict__ act,
    const int* __restrict__ cnt, const int* __restrict__ list,
    const float* __restrict__ voxelwise,
    const float* __restrict__ W1g, const float* __restrict__ W2g,
    const float* __restrict__ fold, float* __restrict__ x17g,
    int* __restrict__ idx)
{
    int n_act = *nact;
    int aidx = blockIdx.x * 4 + (threadIdx.x >> 6);
    if (aidx >= n_act) return;

    int lane = threadIdx.x & 63;
    int g = lane >> 2, ii = lane & 3;
    int cell = act[aidx];
    int numv = min(cnt[cell], 16);
    if (lane == 0) idx[cell] = aidx + 1;

    int myidx = (lane < numv) ? list[cell*16 + lane] : (0x40000000 + lane);
    int rank = 0;
    for (int j = 0; j < numv; j++) { int vj = __shfl(myidx, j); rank += (vj < myidx) ? 1 : 0; }
    if (lane >= numv) rank = lane;
    int sorted = __builtin_amdgcn_ds_permute(rank << 2, myidx);

#define YD(q) float y_##q = 0.f;
    REP16_0(YD)
#undef YD
    for (int p = 0; p < numv; p++) {
        int sv = __shfl(sorted, p);
        float val = voxelwise[sv*64 + lane];
        const float* w = W1g + g*256 + p;
#define BF1(q) y_##q += val * w[(q)*16];
        REP16_0(BF1)
#undef BF1
    }
#define BN1(q) { float yy = y_##q * fold[592 + g*16 + (q)] + fold[848 + g*16 + (q)]; \
    yy = mishf(yy); y_##q = ((q) < numv) ? yy : 0.f; }
    REP16_0(BN1)
#undef BN1

    float z0 = 0.f, z1 = 0.f;
#define BF2(p) z0 += y_##p * W2g[g*32 + (p)]; z1 += y_##p * W2g[g*32 + 16 + (p)];
    REP16_0(BF2)
#undef BF2
    z0 = mishf(z0 * fold[1104 + g*2 + 0] + fold[1136 + g*2 + 0]);
    z1 = mishf(z1 * fold[1104 + g*2 + 1] + fold[1136 + g*2 + 1]);

    int k0 = ii*32 + g*2;
    *(float2*)(x17g + aidx*128 + k0) = make_float2(z0, z1);
}

// ---------------- bfe3 fused: x19 compactly back into x17g ----------------
__global__ __launch_bounds__(512, 4) void bfe3_fused(
    const int* __restrict__ nactp,
    const float* __restrict__ W3, const float* __restrict__ fold,
    float* __restrict__ x17g)
{
    __shared__ float XL[64*128];
    int tid = threadIdx.x;
    int n_act = *nactp;
    int cb = blockIdx.x * 64;

    for (int i = tid; i < 64*32; i += 512) {
        int c = i >> 5, kc = i & 31;
        float4 val = (cb + c < n_act) ? ((const float4*)x17g)[(size_t)(cb+c)*32 + kc]
                                      : make_float4(0.f,0.f,0.f,0.f);
        ((float4*)XL)[c*32 + (kc ^ (c & 31))] = val;
    }
    __syncthreads();

    int wv = __builtin_amdgcn_readfirstlane(tid >> 6);
    int c  = tid & 63;
    int ob = wv * 16;
    int cswz = c & 31;
    const float4* xrow = (const float4*)XL + c*32;
    const float4* W4p = (const float4*)W3;

#define DECLB(q) f32x2 ap_##q = {0.f, 0.f};
#define ACCB(q) { const f32x2* wp_ = (const f32x2*)(W4p + (ob+(q))*32 + kc); \
    ap_##q += xv01 * wp_[0]; ap_##q += xv23 * wp_[1]; }
#define ACTB(q) float a_##q; { float yy = (ap_##q.x + ap_##q.y) * fold[336+ob+(q)] + fold[464+ob+(q)]; a_##q = mishf(yy); }
    {
        REP16_0(DECLB)
        for (int kc = 0; kc < 32; kc++) {
            float4 xv = xrow[kc ^ cswz];
            f32x2 xv01 = {xv.x, xv.y}, xv23 = {xv.z, xv.w};
            REP16_0(ACCB)
        }
        REP16_0(ACTB)
        __syncthreads();
        ((float4*)XL)[c*32 + ((wv*4 + 0) ^ cswz)] = make_float4(a_0,  a_1,  a_2,  a_3);
        ((float4*)XL)[c*32 + ((wv*4 + 1) ^ cswz)] = make_float4(a_4,  a_5,  a_6,  a_7);
        ((float4*)XL)[c*32 + ((wv*4 + 2) ^ cswz)] = make_float4(a_8,  a_9,  a_10, a_11);
        ((float4*)XL)[c*32 + ((wv*4 + 3) ^ cswz)] = make_float4(a_12, a_13, a_14, a_15);
    }
    __syncthreads();

    {
        const float4* yrow = (const float4*)XL + c*32;
        REP16_0(DECLB)
        for (int kc = 0; kc < 32; kc++) {
            float4 xv = yrow[kc ^ cswz];
            f32x2 xv01 = {xv.x, xv.y}, xv23 = {xv.z, xv.w};
            REP16_0(ACCB)
        }
        REP16_0(ACTB)
        float4* dst = (float4*)(x17g + (size_t)(cb + c)*128 + ob);
        dst[0] = make_float4(a_0,  a_1,  a_2,  a_3);
        dst[1] = make_float4(a_4,  a_5,  a_6,  a_7);
        dst[2] = make_float4(a_8,  a_9,  a_10, a_11);
        dst[3] = make_float4(a_12, a_13, a_14, a_15);
    }
#undef DECLB
#undef ACCB
#undef ACTB
}

// ---------------- bev_write: tiled transpose-scatter (replaces out memset) ----------------
__global__ __launch_bounds__(512, 2) void bev_write(
    const int* __restrict__ idx, const float* __restrict__ x19c,
    float* __restrict__ out)
{
    __shared__ float XT[128*65];
    int bid = blockIdx.x;
    int cx = bid % BEVW;
    int cy0 = (bid / BEVW) << 6;
    int tid = threadIdx.x;

    int cell_l = tid >> 3;
    int chq = (tid & 7) << 4;
    int cy = cy0 + cell_l;
    float4 v0 = make_float4(0.f,0.f,0.f,0.f), v1 = v0, v2 = v0, v3 = v0;
    if (cy < BEVH) {
        int ai = idx[cy*BEVW + cx] - 1;
        if (ai >= 0) {
            const float4* src = (const float4*)(x19c + (size_t)ai*128 + chq);
            v0 = src[0]; v1 = src[1]; v2 = src[2]; v3 = src[3];
        }
    }
    float* d = XT + chq*65 + cell_l;
    d[0*65]=v0.x;  d[1*65]=v0.y;  d[2*65]=v0.z;  d[3*65]=v0.w;
    d[4*65]=v1.x;  d[5*65]=v1.y;  d[6*65]=v1.z;  d[7*65]=v1.w;
    d[8*65]=v2.x;  d[9*65]=v2.y;  d[10*65]=v2.z; d[11*65]=v2.w;
    d[12*65]=v3.x; d[13*65]=v3.y; d[14*65]=v3.z; d[15*65]=v3.w;
    __syncthreads();

    int wv2 = tid >> 6, lane = tid & 63;
    int cyw = cy0 + lane;
    if (cyw < BEVH) {
        float* op = out + cx*BEVH + cyw;
#pragma unroll
        for (int k = 0; k < 16; k++) {
            int c = (wv2 << 4) + k;
            op[(size_t)c*NCELL] = XT[c*65 + lane];
        }
    }
}

extern "C" void kernel_launch(void* const* d_in, const int* in_sizes, int n_in,
                              void* d_out, int out_size, void* d_ws, size_t ws_size,
                              hipStream_t stream) {
    const float* features = (const float*)d_in[0];
    const int*   coors    = (const int*)d_in[1];
    const int*   num_vox  = (const int*)d_in[2];
    const float* vfe1_W   = (const float*)d_in[3];
    const float* vfe1_bn  = (const float*)d_in[4];
    const float* vfe2_W   = (const float*)d_in[5];
    const float* vfe2_bn  = (const float*)d_in[6];
    const float* vfe3_W   = (const float*)d_in[7];
    const float* vfe3_bn  = (const float*)d_in[8];
    const float* vfe4_W   = (const float*)d_in[9];
    const float* vfe4_bn  = (const float*)d_in[10];
    const float* bfe1_W   = (const float*)d_in[11];
    const float* bfe1_bn  = (const float*)d_in[12];
    const float* bfe2_W   = (const float*)d_in[13];
    const float* bfe2_bn  = (const float*)d_in[14];
    const float* bfe3_W   = (const float*)d_in[15];
    const float* bfe3_bn  = (const float*)d_in[16];
    float* out = (float*)d_out;

    char* ws = (char*)d_ws;
    int*    nact      = (int*)ws;                       // zeroed
    int*    cnt       = (int*)(ws + 256);               // zeroed
    int*    idx       = (int*)(ws + 857344);            // zeroed (aidx+1 encoding)
    int*    list      = (int*)(ws + 1714432);
    float*  voxelwise = (float*)(ws + 15427840);
    int*    act       = (int*)(ws + 25667840);
    float*  x17g      = (float*)(ws + 25827840);
    float*  fold      = (float*)(ws + 46307840);
    ushort* w4fh      = (ushort*)(ws + 46312512);
    ushort* w4fl      = (ushort*)(ws + 46320704);
    ushort* w3fh      = (ushort*)(ws + 46328896);
    ushort* w3fl      = (ushort*)(ws + 46337088);

    (void)hipMemsetAsync(ws, 0, 1714432, stream);   // nact + cnt + idx in one shot

    setup_kernel<<<1, 256, 0, stream>>>(vfe1_bn, vfe2_bn, vfe3_bn, vfe4_bn,
                                        bfe1_bn, bfe2_bn, bfe3_bn, vfe4_W, vfe3_W,
                                        fold, w4fh, w4fl, w3fh, w3fl);
    vfe_kernel<<<NVOX, 64, 0, stream>>>(features, coors, num_vox,
                                        vfe1_W, vfe2_W, w3fh, w3fl, w4fh, w4fl, fold,
                                        voxelwise, cnt, list, nact, act);
    bfe_front<<<NVOX/4, 256, 0, stream>>>(nact, act, cnt, list, voxelwise,
                                          bfe1_W, bfe2_W, fold, x17g, idx);
    bfe3_fused<<<(NVOX+63)/64, 512, 0, stream>>>(nact, bfe3_W, fold, x17g);
    bev_write<<<BEVW*8, 512, 0, stream>>>(idx, x17g, out);
}

// Round 3
// 530.959 us; speedup vs baseline: 1.3087x; 1.3087x over previous
//
#include <hip/hip_runtime.h>

#define BEVW 432
#define BEVH 496
#define NCELL (BEVW*BEVH)      // 214272
#define NVOX  40000
#define EPSB  1e-5f

typedef float f32x2 __attribute__((ext_vector_type(2)));
typedef float f32x4 __attribute__((ext_vector_type(4)));
typedef unsigned int u32x4 __attribute__((ext_vector_type(4)));
typedef short bf16x8 __attribute__((ext_vector_type(8)));

// ---- repeat macros ----
#define REP8_0(M)  M(0) M(1) M(2) M(3) M(4) M(5) M(6) M(7)
#define REP8_8(M)  M(8) M(9) M(10) M(11) M(12) M(13) M(14) M(15)
#define REP8_16(M) M(16) M(17) M(18) M(19) M(20) M(21) M(22) M(23)
#define REP8_24(M) M(24) M(25) M(26) M(27) M(28) M(29) M(30) M(31)
#define REP16_0(M)  REP8_0(M)  REP8_8(M)
#define REP32_0(M) REP16_0(M) REP8_16(M) REP8_24(M)

// ---------------- workspace layout (bytes) ----------------
// 0        : int nact (zeroed)
// 256      : int cnt[NCELL]  (zeroed)            -> 857344
// 857344   : int idx[NCELL]  (zeroed; aidx+1)    -> 1714432
// 1714432  : int list[NCELL*16]                  -> 15427840
// 15427840 : float voxelwise[NVOX*64]            -> 25667840
// 25667840 : int act[NVOX]                       -> 25827840
// 25827840 : float x17g[NVOX*128] (x17 then x19) -> 46307840
// 46307840 : float fold[1168]
// 46312512 : ushort w4fh[4096] | 46320704: w4fl | 46337088... w3fh@46328896 w3fl@46337088

__device__ __forceinline__ float mishf(float y) {
    float e = __expf(fminf(y, 40.f));
    float n = e * (e + 2.f);
    return y * n * __builtin_amdgcn_rcpf(n + 2.f);
}

template <int CTRL>
__device__ __forceinline__ float dppmaxf(float a) {
    int p = __builtin_amdgcn_update_dpp(0, __float_as_int(a), CTRL, 0xF, 0xF, true);
    return fmaxf(a, __int_as_float(p));
}
#define WMAX32(a) { \
    a = dppmaxf<0xB1>(a); \
    a = dppmaxf<0x4E>(a); \
    a = dppmaxf<0x141>(a); \
    a = dppmaxf<0x140>(a); \
    a = fmaxf(a, __int_as_float(__builtin_amdgcn_ds_swizzle(__float_as_int(a), 0x401F))); }

__device__ __forceinline__ bf16x8 mkbf8(uint a, uint b, uint c, uint d) {
    u32x4 t = {a, b, c, d};
    return __builtin_bit_cast(bf16x8, t);
}

// split fp32 -> (hi bf16 | lo bf16 << 16). Hi = TRUNCATION (1 op); lo = x - hi is
// then exact in fp32, RNE'd to bf16. Combined representation err ~2^-17 rel.
__device__ __forceinline__ uint splitbf(float x) {
    uint rh = __float_as_uint(x) & 0xFFFF0000u;
    float lof = x - __uint_as_float(rh);
    uint ul = __float_as_uint(lof);
    uint rl = (ul + 0x7FFFu + ((ul >> 16) & 1u)) >> 16;
    return (rh >> 16) | (rl << 16);
}

// fold layout: vfe1 s@0 t@8 | vfe2 s@16 t@48 | vfe3 s@80 t@144 | vfe4 s@208 t@272
// bfe3 s@336 t@464 | bfe1 s@592 t@848 | bfe2 s@1104 t@1136
__global__ __launch_bounds__(256) void setup_kernel(
    const float* __restrict__ vbn1, const float* __restrict__ vbn2,
    const float* __restrict__ vbn3, const float* __restrict__ vbn4,
    const float* __restrict__ bbn1, const float* __restrict__ bbn2,
    const float* __restrict__ bbn3, const float* __restrict__ W4,
    const float* __restrict__ W3g,
    float* __restrict__ fold, ushort* __restrict__ w4fh, ushort* __restrict__ w4fl,
    ushort* __restrict__ w3fh, ushort* __restrict__ w3fl)
{
    int tid = threadIdx.x;
    if (tid < 8)  { float s = vbn1[tid]/sqrtf(vbn1[24+tid]+EPSB);  fold[tid]      = s; fold[8+tid]   = vbn1[8+tid]  - vbn1[16+tid]*s; }
    if (tid < 32) { float s = vbn2[tid]/sqrtf(vbn2[96+tid]+EPSB);  fold[16+tid]   = s; fold[48+tid]  = vbn2[32+tid] - vbn2[64+tid]*s; }
    if (tid < 64) { float s = vbn3[tid]/sqrtf(vbn3[192+tid]+EPSB); fold[80+tid]   = s; fold[144+tid] = vbn3[64+tid] - vbn3[128+tid]*s; }
    if (tid < 64) { float s = vbn4[tid]/sqrtf(vbn4[192+tid]+EPSB); fold[208+tid]  = s; fold[272+tid] = vbn4[64+tid] - vbn4[128+tid]*s; }
    if (tid < 128){ float s = bbn3[tid]/sqrtf(bbn3[384+tid]+EPSB); fold[336+tid]  = s; fold[464+tid] = bbn3[128+tid]- bbn3[256+tid]*s; }
    { int g = tid >> 4, q = tid & 15;
      const float* b = bbn1 + g*64;
      float s = b[q]/sqrtf(b[48+q]+EPSB);
      fold[592+tid] = s; fold[848+tid] = b[16+q] - b[32+q]*s; }
    if (tid < 32) { int g = tid >> 1, c = tid & 1;
      const float* b = bbn2 + g*8;
      float s = b[c]/sqrtf(b[6+c]+EPSB);
      fold[1104+tid] = s; fold[1136+tid] = b[2+c] - b[4+c]*s; }

    // B-fragments (B[k][n] = W[n][k]) split bf16 hi/lo, for W4^T and W3^T.
    // frag idx = ((kc*4 + nt)*64 + lane)*8 + j ; n = (lane&15)+16nt ; k = kc*32 + (lane>>4)*8 + j
    for (int i = tid; i < 4096; i += 256) {
        int j = i & 7, ln = (i >> 3) & 63, nt = (i >> 9) & 3, kc = i >> 11;
        int n = (ln & 15) + nt*16;
        int k = kc*32 + (ln >> 4)*8 + j;
        {
            float val = W4[n*64 + k];
            uint rh = __float_as_uint(val) & 0xFFFF0000u;
            float lof = val - __uint_as_float(rh);
            uint ul = __float_as_uint(lof);
            uint rl = (ul + 0x7FFFu + ((ul >> 16) & 1u)) >> 16;
            w4fh[i] = (ushort)(rh >> 16);
            w4fl[i] = (ushort)rl;
        }
        {
            float val = W3g[n*64 + k];
            uint rh = __float_as_uint(val) & 0xFFFF0000u;
            float lof = val - __uint_as_float(rh);
            uint ul = __float_as_uint(lof);
            uint rl = (ul + 0x7FFFu + ((ul >> 16) & 1u)) >> 16;
            w3fh[i] = (ushort)(rh >> 16);
            w3fl[i] = (ushort)rl;
        }
    }
}

// pair list
#define PAIRS(M) M(0,0,1) M(1,2,3) M(2,4,5) M(3,6,7) M(4,8,9) M(5,10,11) \
  M(6,12,13) M(7,14,15) M(8,16,17) M(9,18,19) M(10,20,21) M(11,22,23) \
  M(12,24,25) M(13,26,27) M(14,28,29) M(15,30,31)

#define MF3(D, AH, AL, BH, BL) \
    D = __builtin_amdgcn_mfma_f32_16x16x32_bf16(AL, BH, D, 0, 0, 0); \
    D = __builtin_amdgcn_mfma_f32_16x16x32_bf16(AH, BL, D, 0, 0, 0); \
    D = __builtin_amdgcn_mfma_f32_16x16x32_bf16(AH, BH, D, 0, 0, 0);

// Load one A-tile (16 rows) from LDS rows (stride 33) and pack hi/lo bf16 frags.
#define LDA(SRCP, mt, AH, AL) { \
    const uint* ap_ = (SRCP) + ((lane & 15) + 16*(mt))*33 + quad*8; \
    uint u0 = ap_[0], u1 = ap_[1], u2 = ap_[2], u3 = ap_[3]; \
    uint u4 = ap_[4], u5 = ap_[5], u6 = ap_[6], u7 = ap_[7]; \
    AH = mkbf8(__builtin_amdgcn_perm(u1,u0,0x05040100), __builtin_amdgcn_perm(u3,u2,0x05040100), \
               __builtin_amdgcn_perm(u5,u4,0x05040100), __builtin_amdgcn_perm(u7,u6,0x05040100)); \
    AL = mkbf8(__builtin_amdgcn_perm(u1,u0,0x07060302), __builtin_amdgcn_perm(u3,u2,0x07060302), \
               __builtin_amdgcn_perm(u5,u4,0x07060302), __builtin_amdgcn_perm(u7,u6,0x07060302)); }

// One nt-step: load B pair ONCE, feed 4 A-tiles (4 independent MF3 chains).
#define BSTEP(BHP, BLP, OFS, D0, D1, D2, D3) { \
    uint4 h = (BHP)[OFS]; uint4 l = (BLP)[OFS]; \
    bf16x8 Bh = mkbf8(h.x,h.y,h.z,h.w), Bl = mkbf8(l.x,l.y,l.z,l.w); \
    MF3(D0, Ah0_, Al0_, Bh, Bl) MF3(D1, Ah1_, Al1_, Bh, Bl) \
    MF3(D2, Ah2_, Al2_, Bh, Bl) MF3(D3, Ah3_, Al3_, Bh, Bl) }

// Full 64x64 += 64-rows x 32-K set: A loaded once (4 tiles), each B frag loaded once.
// ACC[mt*4+nt]. Per-accumulator MFMA chain order is IDENTICAL to the 4x DOMTX
// form (bit-identical results); only B loads drop 4x (128KB -> 32KB L1 per wave)
// and each B feeds 4 independent chains (ILP).
#define DOSET(SRCP, BHP, BLP, ACC) { \
    bf16x8 Ah0_, Al0_, Ah1_, Al1_, Ah2_, Al2_, Ah3_, Al3_; \
    LDA(SRCP, 0, Ah0_, Al0_) LDA(SRCP, 1, Ah1_, Al1_) \
    LDA(SRCP, 2, Ah2_, Al2_) LDA(SRCP, 3, Ah3_, Al3_) \
    BSTEP(BHP, BLP, 0,   ACC[0], ACC[4], ACC[8],  ACC[12]) \
    BSTEP(BHP, BLP, 64,  ACC[1], ACC[5], ACC[9],  ACC[13]) \
    BSTEP(BHP, BLP, 128, ACC[2], ACC[6], ACC[10], ACC[14]) \
    BSTEP(BHP, BLP, 192, ACC[3], ACC[7], ACC[11], ACC[15]) }

// ---------------- VFE: single-wave blocks (2 voxels/wave), fe3+fe4 on MFMA ----------------
// Block = 64 threads = 1 wave -> LDS allocation is wave-granular: 163840/17152 = 9
// waves/CU. No __syncthreads needed (all LDS wave-private, DS ops in-order per wave).
// Round-1 lesson: occupancy is NOT the lever (1-voxel/wave raised occ 23->44% and
// regressed) -> per-wave work is. Round-2 lesson: bundling the agg-bias rewrite
// with the B-hoist failed numerics; this round keeps ONLY the provably
// bit-identical B-hoist (DOSET) on the round-0 structure.
__global__ __launch_bounds__(64, 3) void vfe_kernel(
    const float* __restrict__ feat, const int* __restrict__ coors,
    const int* __restrict__ nvx,
    const float* __restrict__ W1, const float* __restrict__ W2,
    const ushort* __restrict__ w3fh, const ushort* __restrict__ w3fl,
    const ushort* __restrict__ w4fh, const ushort* __restrict__ w4fl,
    const float* __restrict__ fold,
    float* __restrict__ voxelwise, int* __restrict__ cnt,
    int* __restrict__ list, int* __restrict__ nact, int* __restrict__ act)
{
    __shared__ char ldsbuf[17152];   // x2s[2][64][33] u32 + aggL[64] f32
    int tid = threadIdx.x;
    int lane = tid;
    int quad = lane >> 4;
    int v = blockIdx.x * 2 + (tid >> 5);
    int vA = blockIdx.x * 2;
    int t = tid & 31;
    uint*  x2s  = (uint*)ldsbuf;
    float* aggL = (float*)(ldsbuf + 16896);

    const float* fp = feat + (v*32 + t)*8;
    float4 fa = *(const float4*)fp;
    float4 fb = *(const float4*)(fp+4);
    int numv = nvx[v];
    float maskf = (t < numv) ? 1.f : 0.f;

    // ---- fe1 (8->8) + pool ----
#define D1(o) float x1_##o; float m1_##o;
    REP8_0(D1)
#undef D1
#define FE1(o) { const float* w = W1 + (o)*8; \
    float ya = fa.x*w[0] + fa.y*w[1]; float yb = fa.z*w[2] + fa.w*w[3]; \
    float yc = fb.x*w[4] + fb.y*w[5]; float yd = fb.z*w[6] + fb.w*w[7]; \
    float yy = ((ya+yb)+(yc+yd)) * fold[(o)] + fold[8+(o)]; \
    x1_##o = mishf(yy); }
    REP8_0(FE1)
#undef FE1
#define P1(o) { float a = x1_##o; WMAX32(a); m1_##o = a; }
    REP8_0(P1)
#undef P1

    f32x2 x1p_0 = {x1_0,x1_1}, x1p_1 = {x1_2,x1_3}, x1p_2 = {x1_4,x1_5}, x1p_3 = {x1_6,x1_7};
    f32x2 m1p_0 = {m1_0,m1_1}, m1p_1 = {m1_2,m1_3}, m1p_2 = {m1_4,m1_5}, m1p_3 = {m1_6,m1_7};

    // ---- fe2 (16->32) + pool ----
#define D2(o) float x2_##o; float agg_##o;
    REP32_0(D2)
#undef D2
#define FE2(o) { const f32x2* wp = (const f32x2*)(W2 + (o)*16); \
    f32x2 sa = x1p_0*wp[0]; sa += x1p_1*wp[1]; \
    f32x2 sb = x1p_2*wp[2]; sb += x1p_3*wp[3]; \
    f32x2 sc = m1p_0*wp[4]; sc += m1p_1*wp[5]; \
    f32x2 sd = m1p_2*wp[6]; sd += m1p_3*wp[7]; \
    sa += sb; sc += sd; sa += sc; \
    float yy = (sa.x + sa.y) * fold[16+(o)] + fold[48+(o)]; \
    x2_##o = mishf(yy); }
    REP32_0(FE2)
#undef FE2
#define P2(o) { float a = x2_##o; WMAX32(a); agg_##o = a; }
    REP32_0(P2)
#undef P2

#define PX(i,a,b) f32x2 x2p_##i = {x2_##a, x2_##b}; f32x2 aggp_##i = {agg_##a, agg_##b};
    PAIRS(PX)
#undef PX

    f32x2 maskp = {maskf, maskf};
#define MSK(i) x2p_##i *= maskp; aggp_##i *= maskp;
    REP16_0(MSK)
#undef MSK

    // aggL: exact fp32 agg (lane t==0 always valid -> masked == unmasked)
    if (t == 0) {
        float* ag = aggL + (lane >> 5)*32;
#define AGW(i) ag[2*(i)] = aggp_##i.x; ag[2*(i)+1] = aggp_##i.y;
        REP16_0(AGW)
#undef AGW
    }

    int nA = __shfl(numv, 0);
    int nB = __shfl(numv, 32);

    // ---- stage masked x2 split into LDS: chunk0 = ch 0..31, chunk1 = ch 32..63 ----
#define X2W(i) { \
    x2s[lane*33 + 2*(i)]          = splitbf(x2p_##i.x); \
    x2s[lane*33 + 2*(i)+1]        = splitbf(x2p_##i.y); \
    x2s[2112 + lane*33 + 2*(i)]   = splitbf(aggp_##i.x); \
    x2s[2112 + lane*33 + 2*(i)+1] = splitbf(aggp_##i.y); }
    REP16_0(X2W)
#undef X2W

    // ---- fe3: 96 MFMAs over K=64 (two 32-K sets) ----
    f32x4 e[16];
#define EIN(i) e[i] = (f32x4){0.f,0.f,0.f,0.f};
    REP16_0(EIN)
#undef EIN
    {
        const uint4* bh3 = (const uint4*)w3fh + lane;
        const uint4* bl3 = (const uint4*)w3fl + lane;
        DOSET(x2s, bh3, bl3, e)
    }
    {
        const uint4* bh3 = (const uint4*)w3fh + 256 + lane;
        const uint4* bl3 = (const uint4*)w3fl + 256 + lane;
        const uint* sp = x2s + 2112;
        DOSET(sp, bh3, bl3, e)
    }

    // ---- fe3 epilogue (bn+mish+split, C-layout) interleaved with fe4 MFMA ----
    int c0 = lane & 15;
    uint* x3st = x2s + 2112;   // agg chunk reused as x3 staging
    f32x4 d[16];
#define DIN(i) d[i] = (f32x4){0.f,0.f,0.f,0.f};
    REP16_0(DIN)
#undef DIN

#define POST(TI, mt, nt) { \
    float s_ = fold[80 + c0 + 16*(nt)], tb_ = fold[144 + c0 + 16*(nt)]; \
    int col_ = c0 + 16*((nt)&1); \
    int rowb_ = quad*4 + 16*(mt); \
    x3st[(rowb_+0)*33 + col_] = splitbf(mishf(e[TI].x * s_ + tb_)); \
    x3st[(rowb_+1)*33 + col_] = splitbf(mishf(e[TI].y * s_ + tb_)); \
    x3st[(rowb_+2)*33 + col_] = splitbf(mishf(e[TI].z * s_ + tb_)); \
    x3st[(rowb_+3)*33 + col_] = splitbf(mishf(e[TI].w * s_ + tb_)); }

    { // output chunk 0: fe3 outputs 0..31 (nt 0,1)
        POST(0,0,0)  POST(1,0,1)
        POST(4,1,0)  POST(5,1,1)
        POST(8,2,0)  POST(9,2,1)
        POST(12,3,0) POST(13,3,1)
        const uint4* bh4 = (const uint4*)w4fh + lane;
        const uint4* bl4 = (const uint4*)w4fl + lane;
        DOSET(x3st, bh4, bl4, d)
    }
    { // output chunk 1: fe3 outputs 32..63 (nt 2,3)
        POST(2,0,2)  POST(3,0,3)
        POST(6,1,2)  POST(7,1,3)
        POST(10,2,2) POST(11,2,3)
        POST(14,3,2) POST(15,3,3)
        const uint4* bh4 = (const uint4*)w4fh + 256 + lane;
        const uint4* bl4 = (const uint4*)w4fl + 256 + lane;
        DOSET(x3st, bh4, bl4, d)
    }
#undef POST

    // ---- bn4 + mish + residual + pool in C layout ----
    float s0f = fold[208+c0],    t0f = fold[272+c0];
    float s1f = fold[208+16+c0], t1f = fold[272+16+c0];
    float s2f = fold[208+32+c0], t2f = fold[272+32+c0];
    float s3f = fold[208+48+c0], t3f = fold[272+48+c0];
    float rA2 = aggL[c0],      rA3 = aggL[16+c0];
    float rB2 = aggL[32+c0],   rB3 = aggL[48+c0];
    float pA0=-3.4e38f, pA1=-3.4e38f, pA2=-3.4e38f, pA3=-3.4e38f;
    float pB0=-3.4e38f, pB1=-3.4e38f, pB2=-3.4e38f, pB3=-3.4e38f;

#define RECON(u) (__uint_as_float((u)<<16) + __uint_as_float((u) & 0xFFFF0000u))
#define FTP(D, mt, nt, SS, TT, PV) { \
    int nv = ((mt) >> 1) ? nB : nA; \
    int rf = quad*4 + 16*(mt); \
    int rt = quad*4 + 16*((mt)&1); \
    int cb = c0 + 16*(nt); \
    float m0=(rt+0<nv)?1.f:0.f, m1=(rt+1<nv)?1.f:0.f, m2=(rt+2<nv)?1.f:0.f, m3=(rt+3<nv)?1.f:0.f; \
    uint ua_ = x2s[(rf+0)*33 + cb], ub_ = x2s[(rf+1)*33 + cb]; \
    uint uc_ = x2s[(rf+2)*33 + cb], ud_ = x2s[(rf+3)*33 + cb]; \
    float y0 = mishf(D.x*SS + TT)*m0 + RECON(ua_); \
    float y1 = mishf(D.y*SS + TT)*m1 + RECON(ub_); \
    float y2 = mishf(D.z*SS + TT)*m2 + RECON(uc_); \
    float y3 = mishf(D.w*SS + TT)*m3 + RECON(ud_); \
    PV = fmaxf(PV, fmaxf(fmaxf(y0,y1), fmaxf(y2,y3))); }

#define FTA(D, mt, nt, SS, TT, AG, PV) { \
    int nv = ((mt) >> 1) ? nB : nA; \
    int rt = quad*4 + 16*((mt)&1); \
    float m0=(rt+0<nv)?1.f:0.f, m1=(rt+1<nv)?1.f:0.f, m2=(rt+2<nv)?1.f:0.f, m3=(rt+3<nv)?1.f:0.f; \
    float y0 = (mishf(D.x*SS + TT) + AG)*m0; \
    float y1 = (mishf(D.y*SS + TT) + AG)*m1; \
    float y2 = (mishf(D.z*SS + TT) + AG)*m2; \
    float y3 = (mishf(D.w*SS + TT) + AG)*m3; \
    PV = fmaxf(PV, fmaxf(fmaxf(y0,y1), fmaxf(y2,y3))); }

    FTP(d[0], 0, 0, s0f, t0f, pA0)  FTP(d[1], 0, 1, s1f, t1f, pA1)
    FTA(d[2], 0, 2, s2f, t2f, rA2, pA2)  FTA(d[3], 0, 3, s3f, t3f, rA3, pA3)
    FTP(d[4], 1, 0, s0f, t0f, pA0)  FTP(d[5], 1, 1, s1f, t1f, pA1)
    FTA(d[6], 1, 2, s2f, t2f, rA2, pA2)  FTA(d[7], 1, 3, s3f, t3f, rA3, pA3)
    FTP(d[8], 2, 0, s0f, t0f, pB0)  FTP(d[9], 2, 1, s1f, t1f, pB1)
    FTA(d[10], 2, 2, s2f, t2f, rB2, pB2)  FTA(d[11], 2, 3, s3f, t3f, rB3, pB3)
    FTP(d[12], 3, 0, s0f, t0f, pB0)  FTP(d[13], 3, 1, s1f, t1f, pB1)
    FTA(d[14], 3, 2, s2f, t2f, rB2, pB2)  FTA(d[15], 3, 3, s3f, t3f, rB3, pB3)
#undef FTP
#undef FTA
#undef RECON

#define RED(p) p = fmaxf(p, __shfl_xor(p, 16)); p = fmaxf(p, __shfl_xor(p, 32));
    RED(pA0) RED(pA1) RED(pA2) RED(pA3) RED(pB0) RED(pB1) RED(pB2) RED(pB3)
#undef RED

    if (quad == 0) {
        float* vwA = voxelwise + vA*64;
        vwA[c0] = pA0; vwA[c0+16] = pA1; vwA[c0+32] = pA2; vwA[c0+48] = pA3;
        float* vwB = voxelwise + (vA+1)*64;
        vwB[c0] = pB0; vwB[c0+16] = pB1; vwB[c0+32] = pB2; vwB[c0+48] = pB3;
    }

    if (t == 0) {
        int cell = coors[v*2] * BEVW + coors[v*2+1];
        int pos = atomicAdd(&cnt[cell], 1);
        if (pos < 16) list[cell*16 + pos] = v;
        if (pos == 0) { int k = atomicAdd(nact, 1); act[k] = cell; }
    }
}

// ---------------- BFE front: 1 wave = 1 cell; records idx[cell]=aidx+1 ----------------
__global__ __launch_bounds__(256) void bfe_front(
    const int* __restrict__ nact, const int* __restrict__ act,
    const int* __restrict__ cnt, const int* __restrict__ list,
    const float* __restrict__ voxelwise,
    const float* __restrict__ W1g, const float* __restrict__ W2g,
    const float* __restrict__ fold, float* __restrict__ x17g,
    int* __restrict__ idx)
{
    int n_act = *nact;
    int aidx = blockIdx.x * 4 + (threadIdx.x >> 6);
    if (aidx >= n_act) return;

    int lane = threadIdx.x & 63;
    int g = lane >> 2, ii = lane & 3;
    int cell = act[aidx];
    int numv = min(cnt[cell], 16);
    if (lane == 0) idx[cell] = aidx + 1;

    int myidx = (lane < numv) ? list[cell*16 + lane] : (0x40000000 + lane);
    int rank = 0;
    for (int j = 0; j < numv; j++) { int vj = __shfl(myidx, j); rank += (vj < myidx) ? 1 : 0; }
    if (lane >= numv) rank = lane;
    int sorted = __builtin_amdgcn_ds_permute(rank << 2, myidx);

#define YD(q) float y_##q = 0.f;
    REP16_0(YD)
#undef YD
    for (int p = 0; p < numv; p++) {
        int sv = __shfl(sorted, p);
        float val = voxelwise[sv*64 + lane];
        const float* w = W1g + g*256 + p;
#define BF1(q) y_##q += val * w[(q)*16];
        REP16_0(BF1)
#undef BF1
    }
#define BN1(q) { float yy = y_##q * fold[592 + g*16 + (q)] + fold[848 + g*16 + (q)]; \
    yy = mishf(yy); y_##q = ((q) < numv) ? yy : 0.f; }
    REP16_0(BN1)
#undef BN1

    float z0 = 0.f, z1 = 0.f;
#define BF2(p) z0 += y_##p * W2g[g*32 + (p)]; z1 += y_##p * W2g[g*32 + 16 + (p)];
    REP16_0(BF2)
#undef BF2
    z0 = mishf(z0 * fold[1104 + g*2 + 0] + fold[1136 + g*2 + 0]);
    z1 = mishf(z1 * fold[1104 + g*2 + 1] + fold[1136 + g*2 + 1]);

    int k0 = ii*32 + g*2;
    *(float2*)(x17g + aidx*128 + k0) = make_float2(z0, z1);
}

// ---------------- bfe3 fused: x19 compactly back into x17g ----------------
__global__ __launch_bounds__(512, 4) void bfe3_fused(
    const int* __restrict__ nactp,
    const float* __restrict__ W3, const float* __restrict__ fold,
    float* __restrict__ x17g)
{
    __shared__ float XL[64*128];
    int tid = threadIdx.x;
    int n_act = *nactp;
    int cb = blockIdx.x * 64;

    for (int i = tid; i < 64*32; i += 512) {
        int c = i >> 5, kc = i & 31;
        float4 val = (cb + c < n_act) ? ((const float4*)x17g)[(size_t)(cb+c)*32 + kc]
                                      : make_float4(0.f,0.f,0.f,0.f);
        ((float4*)XL)[c*32 + (kc ^ (c & 31))] = val;
    }
    __syncthreads();

    int wv = __builtin_amdgcn_readfirstlane(tid >> 6);
    int c  = tid & 63;
    int ob = wv * 16;
    int cswz = c & 31;
    const float4* xrow = (const float4*)XL + c*32;
    const float4* W4p = (const float4*)W3;

#define DECLB(q) f32x2 ap_##q = {0.f, 0.f};
#define ACCB(q) { const f32x2* wp_ = (const f32x2*)(W4p + (ob+(q))*32 + kc); \
    ap_##q += xv01 * wp_[0]; ap_##q += xv23 * wp_[1]; }
#define ACTB(q) float a_##q; { float yy = (ap_##q.x + ap_##q.y) * fold[336+ob+(q)] + fold[464+ob+(q)]; a_##q = mishf(yy); }
    {
        REP16_0(DECLB)
        for (int kc = 0; kc < 32; kc++) {
            float4 xv = xrow[kc ^ cswz];
            f32x2 xv01 = {xv.x, xv.y}, xv23 = {xv.z, xv.w};
            REP16_0(ACCB)
        }
        REP16_0(ACTB)
        __syncthreads();
        ((float4*)XL)[c*32 + ((wv*4 + 0) ^ cswz)] = make_float4(a_0,  a_1,  a_2,  a_3);
        ((float4*)XL)[c*32 + ((wv*4 + 1) ^ cswz)] = make_float4(a_4,  a_5,  a_6,  a_7);
        ((float4*)XL)[c*32 + ((wv*4 + 2) ^ cswz)] = make_float4(a_8,  a_9,  a_10, a_11);
        ((float4*)XL)[c*32 + ((wv*4 + 3) ^ cswz)] = make_float4(a_12, a_13, a_14, a_15);
    }
    __syncthreads();

    {
        const float4* yrow = (const float4*)XL + c*32;
        REP16_0(DECLB)
        for (int kc = 0; kc < 32; kc++) {
            float4 xv = yrow[kc ^ cswz];
            f32x2 xv01 = {xv.x, xv.y}, xv23 = {xv.z, xv.w};
            REP16_0(ACCB)
        }
        REP16_0(ACTB)
        float4* dst = (float4*)(x17g + (size_t)(cb + c)*128 + ob);
        dst[0] = make_float4(a_0,  a_1,  a_2,  a_3);
        dst[1] = make_float4(a_4,  a_5,  a_6,  a_7);
        dst[2] = make_float4(a_8,  a_9,  a_10, a_11);
        dst[3] = make_float4(a_12, a_13, a_14, a_15);
    }
#undef DECLB
#undef ACCB
#undef ACTB
}

// ---------------- bev_write: tiled transpose-scatter (replaces out memset) ----------------
__global__ __launch_bounds__(512, 2) void bev_write(
    const int* __restrict__ idx, const float* __restrict__ x19c,
    float* __restrict__ out)
{
    __shared__ float XT[128*65];
    int bid = blockIdx.x;
    int cx = bid % BEVW;
    int cy0 = (bid / BEVW) << 6;
    int tid = threadIdx.x;

    int cell_l = tid >> 3;
    int chq = (tid & 7) << 4;
    int cy = cy0 + cell_l;
    float4 v0 = make_float4(0.f,0.f,0.f,0.f), v1 = v0, v2 = v0, v3 = v0;
    if (cy < BEVH) {
        int ai = idx[cy*BEVW + cx] - 1;
        if (ai >= 0) {
            const float4* src = (const float4*)(x19c + (size_t)ai*128 + chq);
            v0 = src[0]; v1 = src[1]; v2 = src[2]; v3 = src[3];
        }
    }
    float* d = XT + chq*65 + cell_l;
    d[0*65]=v0.x;  d[1*65]=v0.y;  d[2*65]=v0.z;  d[3*65]=v0.w;
    d[4*65]=v1.x;  d[5*65]=v1.y;  d[6*65]=v1.z;  d[7*65]=v1.w;
    d[8*65]=v2.x;  d[9*65]=v2.y;  d[10*65]=v2.z; d[11*65]=v2.w;
    d[12*65]=v3.x; d[13*65]=v3.y; d[14*65]=v3.z; d[15*65]=v3.w;
    __syncthreads();

    int wv2 = tid >> 6, lane = tid & 63;
    int cyw = cy0 + lane;
    if (cyw < BEVH) {
        float* op = out + cx*BEVH + cyw;
#pragma unroll
        for (int k = 0; k < 16; k++) {
            int c = (wv2 << 4) + k;
            op[(size_t)c*NCELL] = XT[c*65 + lane];
        }
    }
}

extern "C" void kernel_launch(void* const* d_in, const int* in_sizes, int n_in,
                              void* d_out, int out_size, void* d_ws, size_t ws_size,
                              hipStream_t stream) {
    const float* features = (const float*)d_in[0];
    const int*   coors    = (const int*)d_in[1];
    const int*   num_vox  = (const int*)d_in[2];
    const float* vfe1_W   = (const float*)d_in[3];
    const float* vfe1_bn  = (const float*)d_in[4];
    const float* vfe2_W   = (const float*)d_in[5];
    const float* vfe2_bn  = (const float*)d_in[6];
    const float* vfe3_W   = (const float*)d_in[7];
    const float* vfe3_bn  = (const float*)d_in[8];
    const float* vfe4_W   = (const float*)d_in[9];
    const float* vfe4_bn  = (const float*)d_in[10];
    const float* bfe1_W   = (const float*)d_in[11];
    const float* bfe1_bn  = (const float*)d_in[12];
    const float* bfe2_W   = (const float*)d_in[13];
    const float* bfe2_bn  = (const float*)d_in[14];
    const float* bfe3_W   = (const float*)d_in[15];
    const float* bfe3_bn  = (const float*)d_in[16];
    float* out = (float*)d_out;

    char* ws = (char*)d_ws;
    int*    nact      = (int*)ws;                       // zeroed
    int*    cnt       = (int*)(ws + 256);               // zeroed
    int*    idx       = (int*)(ws + 857344);            // zeroed (aidx+1 encoding)
    int*    list      = (int*)(ws + 1714432);
    float*  voxelwise = (float*)(ws + 15427840);
    int*    act       = (int*)(ws + 25667840);
    float*  x17g      = (float*)(ws + 25827840);
    float*  fold      = (float*)(ws + 46307840);
    ushort* w4fh      = (ushort*)(ws + 46312512);
    ushort* w4fl      = (ushort*)(ws + 46320704);
    ushort* w3fh      = (ushort*)(ws + 46328896);
    ushort* w3fl      = (ushort*)(ws + 46337088);

    (void)hipMemsetAsync(ws, 0, 1714432, stream);   // nact + cnt + idx in one shot

    setup_kernel<<<1, 256, 0, stream>>>(vfe1_bn, vfe2_bn, vfe3_bn, vfe4_bn,
                                        bfe1_bn, bfe2_bn, bfe3_bn, vfe4_W, vfe3_W,
                                        fold, w4fh, w4fl, w3fh, w3fl);
    vfe_kernel<<<NVOX/2, 64, 0, stream>>>(features, coors, num_vox,
                                          vfe1_W, vfe2_W, w3fh, w3fl, w4fh, w4fl, fold,
                                          voxelwise, cnt, list, nact, act);
    bfe_front<<<NVOX/4, 256, 0, stream>>>(nact, act, cnt, list, voxelwise,
                                          bfe1_W, bfe2_W, fold, x17g, idx);
    bfe3_fused<<<(NVOX+63)/64, 512, 0, stream>>>(nact, bfe3_W, fold, x17g);
    bev_write<<<BEVW*8, 512, 0, stream>>>(idx, x17g, out);
}

// Round 4
// 515.027 us; speedup vs baseline: 1.3492x; 1.0309x over previous
//
#include <hip/hip_runtime.h>

#define BEVW 432
#define BEVH 496
#define NCELL (BEVW*BEVH)      // 214272
#define NVOX  40000
#define EPSB  1e-5f

typedef float f32x2 __attribute__((ext_vector_type(2)));
typedef float f32x4 __attribute__((ext_vector_type(4)));
typedef unsigned int u32x4 __attribute__((ext_vector_type(4)));
typedef short bf16x8 __attribute__((ext_vector_type(8)));

// ---- repeat macros ----
#define REP8_0(M)  M(0) M(1) M(2) M(3) M(4) M(5) M(6) M(7)
#define REP8_8(M)  M(8) M(9) M(10) M(11) M(12) M(13) M(14) M(15)
#define REP8_16(M) M(16) M(17) M(18) M(19) M(20) M(21) M(22) M(23)
#define REP8_24(M) M(24) M(25) M(26) M(27) M(28) M(29) M(30) M(31)
#define REP16_0(M)  REP8_0(M)  REP8_8(M)
#define REP32_0(M) REP16_0(M) REP8_16(M) REP8_24(M)

// ---------------- workspace layout (bytes) ----------------
// 0        : int nact (zeroed)
// 256      : int cnt[NCELL]  (zeroed)            -> 857344
// 857344   : int idx[NCELL]  (zeroed; aidx+1)    -> 1714432
// 1714432  : int list[NCELL*16]                  -> 15427840
// 15427840 : float voxelwise[NVOX*64]            -> 25667840
// 25667840 : int act[NVOX]                       -> 25827840
// 25827840 : float x17g[NVOX*128] (x17 then x19) -> 46307840
// 46307840 : float fold[1168]
// 46312512 : ushort w4fh[4096] | 46320704: w4fl | 46337088... w3fh@46328896 w3fl@46337088

__device__ __forceinline__ float mishf(float y) {
    float e = __expf(fminf(y, 40.f));
    float n = e * (e + 2.f);
    return y * n * __builtin_amdgcn_rcpf(n + 2.f);
}

template <int CTRL>
__device__ __forceinline__ float dppmaxf(float a) {
    int p = __builtin_amdgcn_update_dpp(0, __float_as_int(a), CTRL, 0xF, 0xF, true);
    return fmaxf(a, __int_as_float(p));
}
#define WMAX32(a) { \
    a = dppmaxf<0xB1>(a); \
    a = dppmaxf<0x4E>(a); \
    a = dppmaxf<0x141>(a); \
    a = dppmaxf<0x140>(a); \
    a = fmaxf(a, __int_as_float(__builtin_amdgcn_ds_swizzle(__float_as_int(a), 0x401F))); }

__device__ __forceinline__ bf16x8 mkbf8(uint a, uint b, uint c, uint d) {
    u32x4 t = {a, b, c, d};
    return __builtin_bit_cast(bf16x8, t);
}

// split fp32 -> (hi bf16 | lo bf16 << 16). Hi = TRUNCATION (1 op); lo = x - hi is
// then exact in fp32, RNE'd to bf16. Combined representation err ~2^-17 rel.
__device__ __forceinline__ uint splitbf(float x) {
    uint rh = __float_as_uint(x) & 0xFFFF0000u;
    float lof = x - __uint_as_float(rh);
    uint ul = __float_as_uint(lof);
    uint rl = (ul + 0x7FFFu + ((ul >> 16) & 1u)) >> 16;
    return (rh >> 16) | (rl << 16);
}

// fold layout: vfe1 s@0 t@8 | vfe2 s@16 t@48 | vfe3 s@80 t@144 | vfe4 s@208 t@272
// bfe3 s@336 t@464 | bfe1 s@592 t@848 | bfe2 s@1104 t@1136
__global__ __launch_bounds__(256) void setup_kernel(
    const float* __restrict__ vbn1, const float* __restrict__ vbn2,
    const float* __restrict__ vbn3, const float* __restrict__ vbn4,
    const float* __restrict__ bbn1, const float* __restrict__ bbn2,
    const float* __restrict__ bbn3, const float* __restrict__ W4,
    const float* __restrict__ W3g,
    float* __restrict__ fold, ushort* __restrict__ w4fh, ushort* __restrict__ w4fl,
    ushort* __restrict__ w3fh, ushort* __restrict__ w3fl)
{
    int tid = threadIdx.x;
    if (tid < 8)  { float s = vbn1[tid]/sqrtf(vbn1[24+tid]+EPSB);  fold[tid]      = s; fold[8+tid]   = vbn1[8+tid]  - vbn1[16+tid]*s; }
    if (tid < 32) { float s = vbn2[tid]/sqrtf(vbn2[96+tid]+EPSB);  fold[16+tid]   = s; fold[48+tid]  = vbn2[32+tid] - vbn2[64+tid]*s; }
    if (tid < 64) { float s = vbn3[tid]/sqrtf(vbn3[192+tid]+EPSB); fold[80+tid]   = s; fold[144+tid] = vbn3[64+tid] - vbn3[128+tid]*s; }
    if (tid < 64) { float s = vbn4[tid]/sqrtf(vbn4[192+tid]+EPSB); fold[208+tid]  = s; fold[272+tid] = vbn4[64+tid] - vbn4[128+tid]*s; }
    if (tid < 128){ float s = bbn3[tid]/sqrtf(bbn3[384+tid]+EPSB); fold[336+tid]  = s; fold[464+tid] = bbn3[128+tid]- bbn3[256+tid]*s; }
    { int g = tid >> 4, q = tid & 15;
      const float* b = bbn1 + g*64;
      float s = b[q]/sqrtf(b[48+q]+EPSB);
      fold[592+tid] = s; fold[848+tid] = b[16+q] - b[32+q]*s; }
    if (tid < 32) { int g = tid >> 1, c = tid & 1;
      const float* b = bbn2 + g*8;
      float s = b[c]/sqrtf(b[6+c]+EPSB);
      fold[1104+tid] = s; fold[1136+tid] = b[2+c] - b[4+c]*s; }

    // B-fragments (B[k][n] = W[n][k]) split bf16 hi/lo, for W4^T and W3^T.
    // frag idx = ((kc*4 + nt)*64 + lane)*8 + j ; n = (lane&15)+16nt ; k = kc*32 + (lane>>4)*8 + j
    for (int i = tid; i < 4096; i += 256) {
        int j = i & 7, ln = (i >> 3) & 63, nt = (i >> 9) & 3, kc = i >> 11;
        int n = (ln & 15) + nt*16;
        int k = kc*32 + (ln >> 4)*8 + j;
        {
            float val = W4[n*64 + k];
            uint rh = __float_as_uint(val) & 0xFFFF0000u;
            float lof = val - __uint_as_float(rh);
            uint ul = __float_as_uint(lof);
            uint rl = (ul + 0x7FFFu + ((ul >> 16) & 1u)) >> 16;
            w4fh[i] = (ushort)(rh >> 16);
            w4fl[i] = (ushort)rl;
        }
        {
            float val = W3g[n*64 + k];
            uint rh = __float_as_uint(val) & 0xFFFF0000u;
            float lof = val - __uint_as_float(rh);
            uint ul = __float_as_uint(lof);
            uint rl = (ul + 0x7FFFu + ((ul >> 16) & 1u)) >> 16;
            w3fh[i] = (ushort)(rh >> 16);
            w3fl[i] = (ushort)rl;
        }
    }
}

// pair list
#define PAIRS(M) M(0,0,1) M(1,2,3) M(2,4,5) M(3,6,7) M(4,8,9) M(5,10,11) \
  M(6,12,13) M(7,14,15) M(8,16,17) M(9,18,19) M(10,20,21) M(11,22,23) \
  M(12,24,25) M(13,26,27) M(14,28,29) M(15,30,31)

#define MF3(D, AH, AL, BH, BL) \
    D = __builtin_amdgcn_mfma_f32_16x16x32_bf16(AL, BH, D, 0, 0, 0); \
    D = __builtin_amdgcn_mfma_f32_16x16x32_bf16(AH, BL, D, 0, 0, 0); \
    D = __builtin_amdgcn_mfma_f32_16x16x32_bf16(AH, BH, D, 0, 0, 0);

// Load one A-tile (16 rows) from LDS rows (stride 33) and pack hi/lo bf16 frags.
#define LDA(SRCP, mt, AH, AL) { \
    const uint* ap_ = (SRCP) + ((lane & 15) + 16*(mt))*33 + quad*8; \
    uint u0 = ap_[0], u1 = ap_[1], u2 = ap_[2], u3 = ap_[3]; \
    uint u4 = ap_[4], u5 = ap_[5], u6 = ap_[6], u7 = ap_[7]; \
    AH = mkbf8(__builtin_amdgcn_perm(u1,u0,0x05040100), __builtin_amdgcn_perm(u3,u2,0x05040100), \
               __builtin_amdgcn_perm(u5,u4,0x05040100), __builtin_amdgcn_perm(u7,u6,0x05040100)); \
    AL = mkbf8(__builtin_amdgcn_perm(u1,u0,0x07060302), __builtin_amdgcn_perm(u3,u2,0x07060302), \
               __builtin_amdgcn_perm(u5,u4,0x07060302), __builtin_amdgcn_perm(u7,u6,0x07060302)); }

// One A-tile vs all 4 B pairs (held in regs): 12 MFMAs, 4 independent chains.
#define TILE4(SRCP, mt, D0, D1, D2, D3) { \
    bf16x8 Ah_, Al_; LDA(SRCP, mt, Ah_, Al_) \
    MF3(D0, Ah_, Al_, B0h_, B0l_) MF3(D1, Ah_, Al_, B1h_, B1l_) \
    MF3(D2, Ah_, Al_, B2h_, B2l_) MF3(D3, Ah_, Al_, B3h_, B3l_) }

// Full 64x64 += 64-rows x 32-K set, with wave-uniform skipping of all-padding
// row tiles (mt=1 when SKA, mt=3 when SKB). B pairs loaded ONCE per set and held.
// Per-accumulator MFMA chain order identical to round-3 DOSET (bit-identical
// results for all computed accumulators; skipped accumulators had zero inputs).
#define DOSET(SRCP, BHP, BLP, ACC, SKA, SKB) { \
    uint4 h0_=(BHP)[0], l0_=(BLP)[0], h1_=(BHP)[64], l1_=(BLP)[64]; \
    uint4 h2_=(BHP)[128], l2_=(BLP)[128], h3_=(BHP)[192], l3_=(BLP)[192]; \
    bf16x8 B0h_=mkbf8(h0_.x,h0_.y,h0_.z,h0_.w), B0l_=mkbf8(l0_.x,l0_.y,l0_.z,l0_.w); \
    bf16x8 B1h_=mkbf8(h1_.x,h1_.y,h1_.z,h1_.w), B1l_=mkbf8(l1_.x,l1_.y,l1_.z,l1_.w); \
    bf16x8 B2h_=mkbf8(h2_.x,h2_.y,h2_.z,h2_.w), B2l_=mkbf8(l2_.x,l2_.y,l2_.z,l2_.w); \
    bf16x8 B3h_=mkbf8(h3_.x,h3_.y,h3_.z,h3_.w), B3l_=mkbf8(l3_.x,l3_.y,l3_.z,l3_.w); \
    TILE4(SRCP, 0, ACC[0], ACC[1], ACC[2], ACC[3]) \
    TILE4(SRCP, 2, ACC[8], ACC[9], ACC[10], ACC[11]) \
    if (!(SKA)) { TILE4(SRCP, 1, ACC[4], ACC[5], ACC[6], ACC[7]) } \
    if (!(SKB)) { TILE4(SRCP, 3, ACC[12], ACC[13], ACC[14], ACC[15]) } }

// ---------------- VFE: single-wave blocks (2 voxels/wave), fe3+fe4 on MFMA ----------------
// Block = 64 threads = 1 wave -> LDS wave-granular: 9 waves/CU. No __syncthreads
// (all LDS wave-private, DS ops in-order per wave).
// Round-1 lesson: occupancy is NOT the lever -> per-wave work is.
// Round-3: DOSET B-hoist, 341->289us. Round-4: wave-uniform dead-tile skip.
// Rows >= numv are zero through fe3/fe4 (masked x2), their fe4 output is masked,
// and they contribute exactly 0 to the pool -> when numv<=16 the upper 16-row
// tile is skippable wholesale (scalar branch; prob 50%); pool seeds 0 instead.
__global__ __launch_bounds__(64, 3) void vfe_kernel(
    const float* __restrict__ feat, const int* __restrict__ coors,
    const int* __restrict__ nvx,
    const float* __restrict__ W1, const float* __restrict__ W2,
    const ushort* __restrict__ w3fh, const ushort* __restrict__ w3fl,
    const ushort* __restrict__ w4fh, const ushort* __restrict__ w4fl,
    const float* __restrict__ fold,
    float* __restrict__ voxelwise, int* __restrict__ cnt,
    int* __restrict__ list, int* __restrict__ nact, int* __restrict__ act)
{
    __shared__ char ldsbuf[17152];   // x2s[2][64][33] u32 + aggL[64] f32
    int tid = threadIdx.x;
    int lane = tid;
    int quad = lane >> 4;
    int v = blockIdx.x * 2 + (tid >> 5);
    int vA = blockIdx.x * 2;
    int t = tid & 31;
    uint*  x2s  = (uint*)ldsbuf;
    float* aggL = (float*)(ldsbuf + 16896);

    const float* fp = feat + (v*32 + t)*8;
    float4 fa = *(const float4*)fp;
    float4 fb = *(const float4*)(fp+4);
    int numv = nvx[v];
    float maskf = (t < numv) ? 1.f : 0.f;

    // ---- fe1 (8->8) + pool ----
#define D1(o) float x1_##o; float m1_##o;
    REP8_0(D1)
#undef D1
#define FE1(o) { const float* w = W1 + (o)*8; \
    float ya = fa.x*w[0] + fa.y*w[1]; float yb = fa.z*w[2] + fa.w*w[3]; \
    float yc = fb.x*w[4] + fb.y*w[5]; float yd = fb.z*w[6] + fb.w*w[7]; \
    float yy = ((ya+yb)+(yc+yd)) * fold[(o)] + fold[8+(o)]; \
    x1_##o = mishf(yy); }
    REP8_0(FE1)
#undef FE1
#define P1(o) { float a = x1_##o; WMAX32(a); m1_##o = a; }
    REP8_0(P1)
#undef P1

    f32x2 x1p_0 = {x1_0,x1_1}, x1p_1 = {x1_2,x1_3}, x1p_2 = {x1_4,x1_5}, x1p_3 = {x1_6,x1_7};
    f32x2 m1p_0 = {m1_0,m1_1}, m1p_1 = {m1_2,m1_3}, m1p_2 = {m1_4,m1_5}, m1p_3 = {m1_6,m1_7};

    // ---- fe2 (16->32) + pool ----
#define D2(o) float x2_##o; float agg_##o;
    REP32_0(D2)
#undef D2
#define FE2(o) { const f32x2* wp = (const f32x2*)(W2 + (o)*16); \
    f32x2 sa = x1p_0*wp[0]; sa += x1p_1*wp[1]; \
    f32x2 sb = x1p_2*wp[2]; sb += x1p_3*wp[3]; \
    f32x2 sc = m1p_0*wp[4]; sc += m1p_1*wp[5]; \
    f32x2 sd = m1p_2*wp[6]; sd += m1p_3*wp[7]; \
    sa += sb; sc += sd; sa += sc; \
    float yy = (sa.x + sa.y) * fold[16+(o)] + fold[48+(o)]; \
    x2_##o = mishf(yy); }
    REP32_0(FE2)
#undef FE2
#define P2(o) { float a = x2_##o; WMAX32(a); agg_##o = a; }
    REP32_0(P2)
#undef P2

#define PX(i,a,b) f32x2 x2p_##i = {x2_##a, x2_##b}; f32x2 aggp_##i = {agg_##a, agg_##b};
    PAIRS(PX)
#undef PX

    f32x2 maskp = {maskf, maskf};
#define MSK(i) x2p_##i *= maskp; aggp_##i *= maskp;
    REP16_0(MSK)
#undef MSK

    // aggL: exact fp32 agg (lane t==0 always valid -> masked == unmasked)
    if (t == 0) {
        float* ag = aggL + (lane >> 5)*32;
#define AGW(i) ag[2*(i)] = aggp_##i.x; ag[2*(i)+1] = aggp_##i.y;
        REP16_0(AGW)
#undef AGW
    }

    int nA = __builtin_amdgcn_readfirstlane(__shfl(numv, 0));
    int nB = __builtin_amdgcn_readfirstlane(__shfl(numv, 32));
    const bool skipA = (nA <= 16);   // voxel A rows 16-31 all padding
    const bool skipB = (nB <= 16);   // voxel B rows 16-31 all padding

    // ---- stage masked x2 split into LDS: chunk0 = ch 0..31, chunk1 = ch 32..63 ----
#define X2W(i) { \
    x2s[lane*33 + 2*(i)]          = splitbf(x2p_##i.x); \
    x2s[lane*33 + 2*(i)+1]        = splitbf(x2p_##i.y); \
    x2s[2112 + lane*33 + 2*(i)]   = splitbf(aggp_##i.x); \
    x2s[2112 + lane*33 + 2*(i)+1] = splitbf(aggp_##i.y); }
    REP16_0(X2W)
#undef X2W

    // ---- fe3: up to 96 MFMAs over K=64 (two 32-K sets), dead tiles skipped ----
    f32x4 e[16];
#define EIN(i) e[i] = (f32x4){0.f,0.f,0.f,0.f};
    REP16_0(EIN)
#undef EIN
    {
        const uint4* bh3 = (const uint4*)w3fh + lane;
        const uint4* bl3 = (const uint4*)w3fl + lane;
        DOSET(x2s, bh3, bl3, e, skipA, skipB)
    }
    {
        const uint4* bh3 = (const uint4*)w3fh + 256 + lane;
        const uint4* bl3 = (const uint4*)w3fl + 256 + lane;
        const uint* sp = x2s + 2112;
        DOSET(sp, bh3, bl3, e, skipA, skipB)
    }

    // ---- fe3 epilogue (bn+mish+split, C-layout) interleaved with fe4 MFMA ----
    int c0 = lane & 15;
    uint* x3st = x2s + 2112;   // agg chunk reused as x3 staging
    f32x4 d[16];
#define DIN(i) d[i] = (f32x4){0.f,0.f,0.f,0.f};
    REP16_0(DIN)
#undef DIN

#define POST(TI, mt, nt) { \
    float s_ = fold[80 + c0 + 16*(nt)], tb_ = fold[144 + c0 + 16*(nt)]; \
    int col_ = c0 + 16*((nt)&1); \
    int rowb_ = quad*4 + 16*(mt); \
    x3st[(rowb_+0)*33 + col_] = splitbf(mishf(e[TI].x * s_ + tb_)); \
    x3st[(rowb_+1)*33 + col_] = splitbf(mishf(e[TI].y * s_ + tb_)); \
    x3st[(rowb_+2)*33 + col_] = splitbf(mishf(e[TI].z * s_ + tb_)); \
    x3st[(rowb_+3)*33 + col_] = splitbf(mishf(e[TI].w * s_ + tb_)); }

    { // output chunk 0: fe3 outputs 0..31 (nt 0,1)
        POST(0,0,0)  POST(1,0,1)
        POST(8,2,0)  POST(9,2,1)
        if (!skipA) { POST(4,1,0)  POST(5,1,1) }
        if (!skipB) { POST(12,3,0) POST(13,3,1) }
        const uint4* bh4 = (const uint4*)w4fh + lane;
        const uint4* bl4 = (const uint4*)w4fl + lane;
        DOSET(x3st, bh4, bl4, d, skipA, skipB)
    }
    { // output chunk 1: fe3 outputs 32..63 (nt 2,3)
        POST(2,0,2)  POST(3,0,3)
        POST(10,2,2) POST(11,2,3)
        if (!skipA) { POST(6,1,2)  POST(7,1,3) }
        if (!skipB) { POST(14,3,2) POST(15,3,3) }
        const uint4* bh4 = (const uint4*)w4fh + 256 + lane;
        const uint4* bl4 = (const uint4*)w4fl + 256 + lane;
        DOSET(x3st, bh4, bl4, d, skipA, skipB)
    }
#undef POST

    // ---- bn4 + mish + residual + pool in C layout ----
    float s0f = fold[208+c0],    t0f = fold[272+c0];
    float s1f = fold[208+16+c0], t1f = fold[272+16+c0];
    float s2f = fold[208+32+c0], t2f = fold[272+32+c0];
    float s3f = fold[208+48+c0], t3f = fold[272+48+c0];
    float rA2 = aggL[c0],      rA3 = aggL[16+c0];
    float rB2 = aggL[32+c0],   rB3 = aggL[48+c0];
    // Skipped tiles' rows would contribute exactly 0 to the pool -> seed 0.
    float piA = skipA ? 0.f : -3.4e38f;
    float piB = skipB ? 0.f : -3.4e38f;
    float pA0=piA, pA1=piA, pA2=piA, pA3=piA;
    float pB0=piB, pB1=piB, pB2=piB, pB3=piB;

#define RECON(u) (__uint_as_float((u)<<16) + __uint_as_float((u) & 0xFFFF0000u))
#define FTP(D, mt, nt, SS, TT, PV) { \
    int nv = ((mt) >> 1) ? nB : nA; \
    int rf = quad*4 + 16*(mt); \
    int rt = quad*4 + 16*((mt)&1); \
    int cb = c0 + 16*(nt); \
    float m0=(rt+0<nv)?1.f:0.f, m1=(rt+1<nv)?1.f:0.f, m2=(rt+2<nv)?1.f:0.f, m3=(rt+3<nv)?1.f:0.f; \
    uint ua_ = x2s[(rf+0)*33 + cb], ub_ = x2s[(rf+1)*33 + cb]; \
    uint uc_ = x2s[(rf+2)*33 + cb], ud_ = x2s[(rf+3)*33 + cb]; \
    float y0 = mishf(D.x*SS + TT)*m0 + RECON(ua_); \
    float y1 = mishf(D.y*SS + TT)*m1 + RECON(ub_); \
    float y2 = mishf(D.z*SS + TT)*m2 + RECON(uc_); \
    float y3 = mishf(D.w*SS + TT)*m3 + RECON(ud_); \
    PV = fmaxf(PV, fmaxf(fmaxf(y0,y1), fmaxf(y2,y3))); }

#define FTA(D, mt, nt, SS, TT, AG, PV) { \
    int nv = ((mt) >> 1) ? nB : nA; \
    int rt = quad*4 + 16*((mt)&1); \
    float m0=(rt+0<nv)?1.f:0.f, m1=(rt+1<nv)?1.f:0.f, m2=(rt+2<nv)?1.f:0.f, m3=(rt+3<nv)?1.f:0.f; \
    float y0 = (mishf(D.x*SS + TT) + AG)*m0; \
    float y1 = (mishf(D.y*SS + TT) + AG)*m1; \
    float y2 = (mishf(D.z*SS + TT) + AG)*m2; \
    float y3 = (mishf(D.w*SS + TT) + AG)*m3; \
    PV = fmaxf(PV, fmaxf(fmaxf(y0,y1), fmaxf(y2,y3))); }

    FTP(d[0], 0, 0, s0f, t0f, pA0)  FTP(d[1], 0, 1, s1f, t1f, pA1)
    FTA(d[2], 0, 2, s2f, t2f, rA2, pA2)  FTA(d[3], 0, 3, s3f, t3f, rA3, pA3)
    if (!skipA) {
        FTP(d[4], 1, 0, s0f, t0f, pA0)  FTP(d[5], 1, 1, s1f, t1f, pA1)
        FTA(d[6], 1, 2, s2f, t2f, rA2, pA2)  FTA(d[7], 1, 3, s3f, t3f, rA3, pA3)
    }
    FTP(d[8], 2, 0, s0f, t0f, pB0)  FTP(d[9], 2, 1, s1f, t1f, pB1)
    FTA(d[10], 2, 2, s2f, t2f, rB2, pB2)  FTA(d[11], 2, 3, s3f, t3f, rB3, pB3)
    if (!skipB) {
        FTP(d[12], 3, 0, s0f, t0f, pB0)  FTP(d[13], 3, 1, s1f, t1f, pB1)
        FTA(d[14], 3, 2, s2f, t2f, rB2, pB2)  FTA(d[15], 3, 3, s3f, t3f, rB3, pB3)
    }
#undef FTP
#undef FTA
#undef RECON

#define RED(p) p = fmaxf(p, __shfl_xor(p, 16)); p = fmaxf(p, __shfl_xor(p, 32));
    RED(pA0) RED(pA1) RED(pA2) RED(pA3) RED(pB0) RED(pB1) RED(pB2) RED(pB3)
#undef RED

    if (quad == 0) {
        float* vwA = voxelwise + vA*64;
        vwA[c0] = pA0; vwA[c0+16] = pA1; vwA[c0+32] = pA2; vwA[c0+48] = pA3;
        float* vwB = voxelwise + (vA+1)*64;
        vwB[c0] = pB0; vwB[c0+16] = pB1; vwB[c0+32] = pB2; vwB[c0+48] = pB3;
    }

    if (t == 0) {
        int cell = coors[v*2] * BEVW + coors[v*2+1];
        int pos = atomicAdd(&cnt[cell], 1);
        if (pos < 16) list[cell*16 + pos] = v;
        if (pos == 0) { int k = atomicAdd(nact, 1); act[k] = cell; }
    }
}

// ---------------- BFE front: 1 wave = 1 cell; records idx[cell]=aidx+1 ----------------
__global__ __launch_bounds__(256) void bfe_front(
    const int* __restrict__ nact, const int* __restrict__ act,
    const int* __restrict__ cnt, const int* __restrict__ list,
    const float* __restrict__ voxelwise,
    const float* __restrict__ W1g, const float* __restrict__ W2g,
    const float* __restrict__ fold, float* __restrict__ x17g,
    int* __restrict__ idx)
{
    int n_act = *nact;
    int aidx = blockIdx.x * 4 + (threadIdx.x >> 6);
    if (aidx >= n_act) return;

    int lane = threadIdx.x & 63;
    int g = lane >> 2, ii = lane & 3;
    int cell = act[aidx];
    int numv = min(cnt[cell], 16);
    if (lane == 0) idx[cell] = aidx + 1;

    int myidx = (lane < numv) ? list[cell*16 + lane] : (0x40000000 + lane);
    int rank = 0;
    for (int j = 0; j < numv; j++) { int vj = __shfl(myidx, j); rank += (vj < myidx) ? 1 : 0; }
    if (lane >= numv) rank = lane;
    int sorted = __builtin_amdgcn_ds_permute(rank << 2, myidx);

#define YD(q) float y_##q = 0.f;
    REP16_0(YD)
#undef YD
    for (int p = 0; p < numv; p++) {
        int sv = __shfl(sorted, p);
        float val = voxelwise[sv*64 + lane];
        const float* w = W1g + g*256 + p;
#define BF1(q) y_##q += val * w[(q)*16];
        REP16_0(BF1)
#undef BF1
    }
#define BN1(q) { float yy = y_##q * fold[592 + g*16 + (q)] + fold[848 + g*16 + (q)]; \
    yy = mishf(yy); y_##q = ((q) < numv) ? yy : 0.f; }
    REP16_0(BN1)
#undef BN1

    float z0 = 0.f, z1 = 0.f;
#define BF2(p) z0 += y_##p * W2g[g*32 + (p)]; z1 += y_##p * W2g[g*32 + 16 + (p)];
    REP16_0(BF2)
#undef BF2
    z0 = mishf(z0 * fold[1104 + g*2 + 0] + fold[1136 + g*2 + 0]);
    z1 = mishf(z1 * fold[1104 + g*2 + 1] + fold[1136 + g*2 + 1]);

    int k0 = ii*32 + g*2;
    *(float2*)(x17g + aidx*128 + k0) = make_float2(z0, z1);
}

// ---------------- bfe3 fused: x19 compactly back into x17g ----------------
__global__ __launch_bounds__(512, 4) void bfe3_fused(
    const int* __restrict__ nactp,
    const float* __restrict__ W3, const float* __restrict__ fold,
    float* __restrict__ x17g)
{
    __shared__ float XL[64*128];
    int tid = threadIdx.x;
    int n_act = *nactp;
    int cb = blockIdx.x * 64;

    for (int i = tid; i < 64*32; i += 512) {
        int c = i >> 5, kc = i & 31;
        float4 val = (cb + c < n_act) ? ((const float4*)x17g)[(size_t)(cb+c)*32 + kc]
                                      : make_float4(0.f,0.f,0.f,0.f);
        ((float4*)XL)[c*32 + (kc ^ (c & 31))] = val;
    }
    __syncthreads();

    int wv = __builtin_amdgcn_readfirstlane(tid >> 6);
    int c  = tid & 63;
    int ob = wv * 16;
    int cswz = c & 31;
    const float4* xrow = (const float4*)XL + c*32;
    const float4* W4p = (const float4*)W3;

#define DECLB(q) f32x2 ap_##q = {0.f, 0.f};
#define ACCB(q) { const f32x2* wp_ = (const f32x2*)(W4p + (ob+(q))*32 + kc); \
    ap_##q += xv01 * wp_[0]; ap_##q += xv23 * wp_[1]; }
#define ACTB(q) float a_##q; { float yy = (ap_##q.x + ap_##q.y) * fold[336+ob+(q)] + fold[464+ob+(q)]; a_##q = mishf(yy); }
    {
        REP16_0(DECLB)
        for (int kc = 0; kc < 32; kc++) {
            float4 xv = xrow[kc ^ cswz];
            f32x2 xv01 = {xv.x, xv.y}, xv23 = {xv.z, xv.w};
            REP16_0(ACCB)
        }
        REP16_0(ACTB)
        __syncthreads();
        ((float4*)XL)[c*32 + ((wv*4 + 0) ^ cswz)] = make_float4(a_0,  a_1,  a_2,  a_3);
        ((float4*)XL)[c*32 + ((wv*4 + 1) ^ cswz)] = make_float4(a_4,  a_5,  a_6,  a_7);
        ((float4*)XL)[c*32 + ((wv*4 + 2) ^ cswz)] = make_float4(a_8,  a_9,  a_10, a_11);
        ((float4*)XL)[c*32 + ((wv*4 + 3) ^ cswz)] = make_float4(a_12, a_13, a_14, a_15);
    }
    __syncthreads();

    {
        const float4* yrow = (const float4*)XL + c*32;
        REP16_0(DECLB)
        for (int kc = 0; kc < 32; kc++) {
            float4 xv = yrow[kc ^ cswz];
            f32x2 xv01 = {xv.x, xv.y}, xv23 = {xv.z, xv.w};
            REP16_0(ACCB)
        }
        REP16_0(ACTB)
        float4* dst = (float4*)(x17g + (size_t)(cb + c)*128 + ob);
        dst[0] = make_float4(a_0,  a_1,  a_2,  a_3);
        dst[1] = make_float4(a_4,  a_5,  a_6,  a_7);
        dst[2] = make_float4(a_8,  a_9,  a_10, a_11);
        dst[3] = make_float4(a_12, a_13, a_14, a_15);
    }
#undef DECLB
#undef ACCB
#undef ACTB
}

// ---------------- bev_write: tiled transpose-scatter (replaces out memset) ----------------
__global__ __launch_bounds__(512, 2) void bev_write(
    const int* __restrict__ idx, const float* __restrict__ x19c,
    float* __restrict__ out)
{
    __shared__ float XT[128*65];
    int bid = blockIdx.x;
    int cx = bid % BEVW;
    int cy0 = (bid / BEVW) << 6;
    int tid = threadIdx.x;

    int cell_l = tid >> 3;
    int chq = (tid & 7) << 4;
    int cy = cy0 + cell_l;
    float4 v0 = make_float4(0.f,0.f,0.f,0.f), v1 = v0, v2 = v0, v3 = v0;
    if (cy < BEVH) {
        int ai = idx[cy*BEVW + cx] - 1;
        if (ai >= 0) {
            const float4* src = (const float4*)(x19c + (size_t)ai*128 + chq);
            v0 = src[0]; v1 = src[1]; v2 = src[2]; v3 = src[3];
        }
    }
    float* d = XT + chq*65 + cell_l;
    d[0*65]=v0.x;  d[1*65]=v0.y;  d[2*65]=v0.z;  d[3*65]=v0.w;
    d[4*65]=v1.x;  d[5*65]=v1.y;  d[6*65]=v1.z;  d[7*65]=v1.w;
    d[8*65]=v2.x;  d[9*65]=v2.y;  d[10*65]=v2.z; d[11*65]=v2.w;
    d[12*65]=v3.x; d[13*65]=v3.y; d[14*65]=v3.z; d[15*65]=v3.w;
    __syncthreads();

    int wv2 = tid >> 6, lane = tid & 63;
    int cyw = cy0 + lane;
    if (cyw < BEVH) {
        float* op = out + cx*BEVH + cyw;
#pragma unroll
        for (int k = 0; k < 16; k++) {
            int c = (wv2 << 4) + k;
            op[(size_t)c*NCELL] = XT[c*65 + lane];
        }
    }
}

extern "C" void kernel_launch(void* const* d_in, const int* in_sizes, int n_in,
                              void* d_out, int out_size, void* d_ws, size_t ws_size,
                              hipStream_t stream) {
    const float* features = (const float*)d_in[0];
    const int*   coors    = (const int*)d_in[1];
    const int*   num_vox  = (const int*)d_in[2];
    const float* vfe1_W   = (const float*)d_in[3];
    const float* vfe1_bn  = (const float*)d_in[4];
    const float* vfe2_W   = (const float*)d_in[5];
    const float* vfe2_bn  = (const float*)d_in[6];
    const float* vfe3_W   = (const float*)d_in[7];
    const float* vfe3_bn  = (const float*)d_in[8];
    const float* vfe4_W   = (const float*)d_in[9];
    const float* vfe4_bn  = (const float*)d_in[10];
    const float* bfe1_W   = (const float*)d_in[11];
    const float* bfe1_bn  = (const float*)d_in[12];
    const float* bfe2_W   = (const float*)d_in[13];
    const float* bfe2_bn  = (const float*)d_in[14];
    const float* bfe3_W   = (const float*)d_in[15];
    const float* bfe3_bn  = (const float*)d_in[16];
    float* out = (float*)d_out;

    char* ws = (char*)d_ws;
    int*    nact      = (int*)ws;                       // zeroed
    int*    cnt       = (int*)(ws + 256);               // zeroed
    int*    idx       = (int*)(ws + 857344);            // zeroed (aidx+1 encoding)
    int*    list      = (int*)(ws + 1714432);
    float*  voxelwise = (float*)(ws + 15427840);
    int*    act       = (int*)(ws + 25667840);
    float*  x17g      = (float*)(ws + 25827840);
    float*  fold      = (float*)(ws + 46307840);
    ushort* w4fh      = (ushort*)(ws + 46312512);
    ushort* w4fl      = (ushort*)(ws + 46320704);
    ushort* w3fh      = (ushort*)(ws + 46328896);
    ushort* w3fl      = (ushort*)(ws + 46337088);

    (void)hipMemsetAsync(ws, 0, 1714432, stream);   // nact + cnt + idx in one shot

    setup_kernel<<<1, 256, 0, stream>>>(vfe1_bn, vfe2_bn, vfe3_bn, vfe4_bn,
                                        bfe1_bn, bfe2_bn, bfe3_bn, vfe4_W, vfe3_W,
                                        fold, w4fh, w4fl, w3fh, w3fl);
    vfe_kernel<<<NVOX/2, 64, 0, stream>>>(features, coors, num_vox,
                                          vfe1_W, vfe2_W, w3fh, w3fl, w4fh, w4fl, fold,
                                          voxelwise, cnt, list, nact, act);
    bfe_front<<<NVOX/4, 256, 0, stream>>>(nact, act, cnt, list, voxelwise,
                                          bfe1_W, bfe2_W, fold, x17g, idx);
    bfe3_fused<<<(NVOX+63)/64, 512, 0, stream>>>(nact, bfe3_W, fold, x17g);
    bev_write<<<BEVW*8, 512, 0, stream>>>(idx, x17g, out);
}

// Round 5
// 508.913 us; speedup vs baseline: 1.3654x; 1.0120x over previous
//
#include <hip/hip_runtime.h>

#define BEVW 432
#define BEVH 496
#define NCELL (BEVW*BEVH)      // 214272
#define NVOX  40000
#define EPSB  1e-5f

typedef float f32x2 __attribute__((ext_vector_type(2)));
typedef float f32x4 __attribute__((ext_vector_type(4)));
typedef unsigned int u32x4 __attribute__((ext_vector_type(4)));
typedef short bf16x8 __attribute__((ext_vector_type(8)));

// ---- repeat macros ----
#define REP8_0(M)  M(0) M(1) M(2) M(3) M(4) M(5) M(6) M(7)
#define REP8_8(M)  M(8) M(9) M(10) M(11) M(12) M(13) M(14) M(15)
#define REP16_0(M)  REP8_0(M)  REP8_8(M)

// ---------------- workspace layout (bytes) ----------------
// 0        : int nact (zeroed)
// 256      : int cnt[NCELL]  (zeroed)            -> 857344
// 857344   : int idx[NCELL]  (zeroed; aidx+1)    -> 1714432
// 1714432  : int list[NCELL*16]                  -> 15427840
// 15427840 : float voxelwise[NVOX*64]            -> 25667840
// 25667840 : int act[NVOX]                       -> 25827840
// 25827840 : float x17g[NVOX*128] (x17 then x19) -> 46307840
// 46307840 : float fold[1168]
// 46312512 : w4fh | 46320704: w4fl | 46328896: w3fh | 46337088: w3fl
// 46345280 : w2fh[1024] | 46347328 : w2fl[1024]

__device__ __forceinline__ float mishf(float y) {
    float e = __expf(fminf(y, 40.f));
    float n = e * (e + 2.f);
    return y * n * __builtin_amdgcn_rcpf(n + 2.f);
}

template <int CTRL>
__device__ __forceinline__ float dppmaxf(float a) {
    int p = __builtin_amdgcn_update_dpp(0, __float_as_int(a), CTRL, 0xF, 0xF, true);
    return fmaxf(a, __int_as_float(p));
}
#define WMAX32(a) { \
    a = dppmaxf<0xB1>(a); \
    a = dppmaxf<0x4E>(a); \
    a = dppmaxf<0x141>(a); \
    a = dppmaxf<0x140>(a); \
    a = fmaxf(a, __int_as_float(__builtin_amdgcn_ds_swizzle(__float_as_int(a), 0x401F))); }

__device__ __forceinline__ bf16x8 mkbf8(uint a, uint b, uint c, uint d) {
    u32x4 t = {a, b, c, d};
    return __builtin_bit_cast(bf16x8, t);
}

// split fp32 -> (hi bf16 | lo bf16 << 16). Hi = TRUNCATION (1 op); lo = x - hi is
// then exact in fp32, RNE'd to bf16. Combined representation err ~2^-17 rel.
__device__ __forceinline__ uint splitbf(float x) {
    uint rh = __float_as_uint(x) & 0xFFFF0000u;
    float lof = x - __uint_as_float(rh);
    uint ul = __float_as_uint(lof);
    uint rl = (ul + 0x7FFFu + ((ul >> 16) & 1u)) >> 16;
    return (rh >> 16) | (rl << 16);
}

// fold layout: vfe1 s@0 t@8 | vfe2 s@16 t@48 | vfe3 s@80 t@144 | vfe4 s@208 t@272
// bfe3 s@336 t@464 | bfe1 s@592 t@848 | bfe2 s@1104 t@1136
__global__ __launch_bounds__(256) void setup_kernel(
    const float* __restrict__ vbn1, const float* __restrict__ vbn2,
    const float* __restrict__ vbn3, const float* __restrict__ vbn4,
    const float* __restrict__ bbn1, const float* __restrict__ bbn2,
    const float* __restrict__ bbn3, const float* __restrict__ W4,
    const float* __restrict__ W3g, const float* __restrict__ W2g,
    float* __restrict__ fold, ushort* __restrict__ w4fh, ushort* __restrict__ w4fl,
    ushort* __restrict__ w3fh, ushort* __restrict__ w3fl,
    ushort* __restrict__ w2fh, ushort* __restrict__ w2fl)
{
    int tid = threadIdx.x;
    if (tid < 8)  { float s = vbn1[tid]/sqrtf(vbn1[24+tid]+EPSB);  fold[tid]      = s; fold[8+tid]   = vbn1[8+tid]  - vbn1[16+tid]*s; }
    if (tid < 32) { float s = vbn2[tid]/sqrtf(vbn2[96+tid]+EPSB);  fold[16+tid]   = s; fold[48+tid]  = vbn2[32+tid] - vbn2[64+tid]*s; }
    if (tid < 64) { float s = vbn3[tid]/sqrtf(vbn3[192+tid]+EPSB); fold[80+tid]   = s; fold[144+tid] = vbn3[64+tid] - vbn3[128+tid]*s; }
    if (tid < 64) { float s = vbn4[tid]/sqrtf(vbn4[192+tid]+EPSB); fold[208+tid]  = s; fold[272+tid] = vbn4[64+tid] - vbn4[128+tid]*s; }
    if (tid < 128){ float s = bbn3[tid]/sqrtf(bbn3[384+tid]+EPSB); fold[336+tid]  = s; fold[464+tid] = bbn3[128+tid]- bbn3[256+tid]*s; }
    { int g = tid >> 4, q = tid & 15;
      const float* b = bbn1 + g*64;
      float s = b[q]/sqrtf(b[48+q]+EPSB);
      fold[592+tid] = s; fold[848+tid] = b[16+q] - b[32+q]*s; }
    if (tid < 32) { int g = tid >> 1, c = tid & 1;
      const float* b = bbn2 + g*8;
      float s = b[c]/sqrtf(b[6+c]+EPSB);
      fold[1104+tid] = s; fold[1136+tid] = b[2+c] - b[4+c]*s; }

    // B-fragments (B[k][n] = W[n][k]) split bf16 hi/lo, for W4^T and W3^T.
    // frag idx = ((kc*4 + nt)*64 + lane)*8 + j ; n = (lane&15)+16nt ; k = kc*32 + (lane>>4)*8 + j
    for (int i = tid; i < 4096; i += 256) {
        int j = i & 7, ln = (i >> 3) & 63, nt = (i >> 9) & 3, kc = i >> 11;
        int n = (ln & 15) + nt*16;
        int k = kc*32 + (ln >> 4)*8 + j;
        {
            float val = W4[n*64 + k];
            uint u = splitbf(val);
            w4fh[i] = (ushort)(u & 0xFFFFu);
            w4fl[i] = (ushort)(u >> 16);
        }
        {
            float val = W3g[n*64 + k];
            uint u = splitbf(val);
            w3fh[i] = (ushort)(u & 0xFFFFu);
            w3fl[i] = (ushort)(u >> 16);
        }
    }

    // W2 B-fragments: K=16 padded to 32 with ZERO weights (k>=16 -> 0), N=32.
    // frag idx = (nt*64 + lane)*8 + j ; n = (lane&15)+16nt ; k = (lane>>4)*8 + j
    for (int i = tid; i < 1024; i += 256) {
        int j = i & 7, ln = (i >> 3) & 63, nt = (i >> 9) & 1;
        int n = (ln & 15) + nt*16;
        int k = (ln >> 4)*8 + j;
        float val = (k < 16) ? W2g[n*16 + k] : 0.f;
        uint u = splitbf(val);
        w2fh[i] = (ushort)(u & 0xFFFFu);
        w2fl[i] = (ushort)(u >> 16);
    }
}

#define MF3(D, AH, AL, BH, BL) \
    D = __builtin_amdgcn_mfma_f32_16x16x32_bf16(AL, BH, D, 0, 0, 0); \
    D = __builtin_amdgcn_mfma_f32_16x16x32_bf16(AH, BL, D, 0, 0, 0); \
    D = __builtin_amdgcn_mfma_f32_16x16x32_bf16(AH, BH, D, 0, 0, 0);

// Load one A-tile (16 rows) from LDS rows (stride 33) and pack hi/lo bf16 frags.
#define LDA(SRCP, mt, AH, AL) { \
    const uint* ap_ = (SRCP) + ((lane & 15) + 16*(mt))*33 + quad*8; \
    uint u0 = ap_[0], u1 = ap_[1], u2 = ap_[2], u3 = ap_[3]; \
    uint u4 = ap_[4], u5 = ap_[5], u6 = ap_[6], u7 = ap_[7]; \
    AH = mkbf8(__builtin_amdgcn_perm(u1,u0,0x05040100), __builtin_amdgcn_perm(u3,u2,0x05040100), \
               __builtin_amdgcn_perm(u5,u4,0x05040100), __builtin_amdgcn_perm(u7,u6,0x05040100)); \
    AL = mkbf8(__builtin_amdgcn_perm(u1,u0,0x07060302), __builtin_amdgcn_perm(u3,u2,0x07060302), \
               __builtin_amdgcn_perm(u5,u4,0x07060302), __builtin_amdgcn_perm(u7,u6,0x07060302)); }

// fe2 A-tile: K=16 real data in cols 0-15. Quads 2,3 (k 16-31) RE-READ cols 0-15
// ((quad&1) addressing) so A stays finite; their B weights are exactly 0 -> no
// NaN·0 hazard and no contribution.
#define LDA2(SRCP, mt, AH, AL) { \
    const uint* ap_ = (SRCP) + ((lane & 15) + 16*(mt))*33 + (quad & 1)*8; \
    uint u0 = ap_[0], u1 = ap_[1], u2 = ap_[2], u3 = ap_[3]; \
    uint u4 = ap_[4], u5 = ap_[5], u6 = ap_[6], u7 = ap_[7]; \
    AH = mkbf8(__builtin_amdgcn_perm(u1,u0,0x05040100), __builtin_amdgcn_perm(u3,u2,0x05040100), \
               __builtin_amdgcn_perm(u5,u4,0x05040100), __builtin_amdgcn_perm(u7,u6,0x05040100)); \
    AL = mkbf8(__builtin_amdgcn_perm(u1,u0,0x07060302), __builtin_amdgcn_perm(u3,u2,0x07060302), \
               __builtin_amdgcn_perm(u5,u4,0x07060302), __builtin_amdgcn_perm(u7,u6,0x07060302)); }

// One A-tile vs all 4 B pairs (held in regs): 12 MFMAs, 4 independent chains.
#define TILE4(SRCP, mt, D0, D1, D2, D3) { \
    bf16x8 Ah_, Al_; LDA(SRCP, mt, Ah_, Al_) \
    MF3(D0, Ah_, Al_, B0h_, B0l_) MF3(D1, Ah_, Al_, B1h_, B1l_) \
    MF3(D2, Ah_, Al_, B2h_, B2l_) MF3(D3, Ah_, Al_, B3h_, B3l_) }

// Full 64x64 += 64-rows x 32-K set, with wave-uniform skipping of all-padding
// row tiles (mt=1 when SKA, mt=3 when SKB). B pairs loaded ONCE per set and held.
#define DOSET(SRCP, BHP, BLP, ACC, SKA, SKB) { \
    uint4 h0_=(BHP)[0], l0_=(BLP)[0], h1_=(BHP)[64], l1_=(BLP)[64]; \
    uint4 h2_=(BHP)[128], l2_=(BLP)[128], h3_=(BHP)[192], l3_=(BLP)[192]; \
    bf16x8 B0h_=mkbf8(h0_.x,h0_.y,h0_.z,h0_.w), B0l_=mkbf8(l0_.x,l0_.y,l0_.z,l0_.w); \
    bf16x8 B1h_=mkbf8(h1_.x,h1_.y,h1_.z,h1_.w), B1l_=mkbf8(l1_.x,l1_.y,l1_.z,l1_.w); \
    bf16x8 B2h_=mkbf8(h2_.x,h2_.y,h2_.z,h2_.w), B2l_=mkbf8(l2_.x,l2_.y,l2_.z,l2_.w); \
    bf16x8 B3h_=mkbf8(h3_.x,h3_.y,h3_.z,h3_.w), B3l_=mkbf8(l3_.x,l3_.y,l3_.z,l3_.w); \
    TILE4(SRCP, 0, ACC[0], ACC[1], ACC[2], ACC[3]) \
    TILE4(SRCP, 2, ACC[8], ACC[9], ACC[10], ACC[11]) \
    if (!(SKA)) { TILE4(SRCP, 1, ACC[4], ACC[5], ACC[6], ACC[7]) } \
    if (!(SKB)) { TILE4(SRCP, 3, ACC[12], ACC[13], ACC[14], ACC[15]) } }

// ---------------- VFE: single-wave blocks (2 voxels/wave), fe2+fe3+fe4 on MFMA ----------------
// Block = 64 threads = 1 wave -> LDS wave-granular: 9 waves/CU. No __syncthreads
// (all LDS wave-private, DS ops in-order per wave).
// R1: occupancy not the lever -> per-wave work is. R3: DOSET B-hoist 341->289.
// R4: dead-tile skip 289->262. R5: fe2 moved to MFMA — removes the 32-ch VALU dot
// (~510 i/lane), the WMAX32 pool (~320), and 64->~40 splitbf in staging.
// fe3 onward is byte-identical to R4; chunk0/chunk1/aggL keep identical layout.
__global__ __launch_bounds__(64, 3) void vfe_kernel(
    const float* __restrict__ feat, const int* __restrict__ coors,
    const int* __restrict__ nvx,
    const float* __restrict__ W1,
    const ushort* __restrict__ w2fh, const ushort* __restrict__ w2fl,
    const ushort* __restrict__ w3fh, const ushort* __restrict__ w3fl,
    const ushort* __restrict__ w4fh, const ushort* __restrict__ w4fl,
    const float* __restrict__ fold,
    float* __restrict__ voxelwise, int* __restrict__ cnt,
    int* __restrict__ list, int* __restrict__ nact, int* __restrict__ act)
{
    __shared__ char ldsbuf[17152];   // x2s[2][64][33] u32 + aggL[64] f32
    int tid = threadIdx.x;
    int lane = tid;
    int quad = lane >> 4;
    int c0 = lane & 15;
    int v = blockIdx.x * 2 + (tid >> 5);
    int vA = blockIdx.x * 2;
    int t = tid & 31;
    uint*  x2s  = (uint*)ldsbuf;
    uint*  x2s1 = x2s + 2112;        // chunk1
    float* aggL = (float*)(ldsbuf + 16896);

    const float* fp = feat + (v*32 + t)*8;
    float4 fa = *(const float4*)(fp);
    float4 fb = *(const float4*)(fp+4);
    int numv = nvx[v];

    // ---- fe1 (8->8) + pool (VALU; lane owns row t of its voxel; row index == lane) ----
#define D1(o) float x1_##o; float m1_##o;
    REP8_0(D1)
#undef D1
#define FE1(o) { const float* w = W1 + (o)*8; \
    float ya = fa.x*w[0] + fa.y*w[1]; float yb = fa.z*w[2] + fa.w*w[3]; \
    float yc = fb.x*w[4] + fb.y*w[5]; float yd = fb.z*w[6] + fb.w*w[7]; \
    float yy = ((ya+yb)+(yc+yd)) * fold[(o)] + fold[8+(o)]; \
    x1_##o = mishf(yy); }
    REP8_0(FE1)
#undef FE1
#define P1(o) { float a = x1_##o; WMAX32(a); m1_##o = a; }
    REP8_0(P1)
#undef P1

    int nA = __builtin_amdgcn_readfirstlane(__shfl(numv, 0));
    int nB = __builtin_amdgcn_readfirstlane(__shfl(numv, 32));
    const bool skipA = (nA <= 16);   // voxel A rows 16-31 all padding
    const bool skipB = (nB <= 16);   // voxel B rows 16-31 all padding

    // ---- stage fe2 A-operand: concat(x1, m1) split-bf16, row = lane, cols 0-15 ----
#define S1(o) { x2s1[lane*33 + (o)] = splitbf(x1_##o); x2s1[lane*33 + 8 + (o)] = splitbf(m1_##o); }
    REP8_0(S1)
#undef S1

    // ---- fe2 on MFMA: 64x32 <- 64x16 (K padded to 32 w/ zero B), 24 MFMAs ----
    // acc f2[mt*2+nt]: rows quad*4+i+16mt, channel c0+16nt
    f32x4 f2[8];
#pragma unroll
    for (int i = 0; i < 8; i++) f2[i] = (f32x4){0.f,0.f,0.f,0.f};
    {
        const uint4* bh2 = (const uint4*)w2fh + lane;
        const uint4* bl2 = (const uint4*)w2fl + lane;
        uint4 h0_=bh2[0], l0_=bl2[0], h1_=bh2[64], l1_=bl2[64];
        bf16x8 B0h_=mkbf8(h0_.x,h0_.y,h0_.z,h0_.w), B0l_=mkbf8(l0_.x,l0_.y,l0_.z,l0_.w);
        bf16x8 B1h_=mkbf8(h1_.x,h1_.y,h1_.z,h1_.w), B1l_=mkbf8(l1_.x,l1_.y,l1_.z,l1_.w);
        { bf16x8 Ah_,Al_; LDA2(x2s1,0,Ah_,Al_) MF3(f2[0],Ah_,Al_,B0h_,B0l_) MF3(f2[1],Ah_,Al_,B1h_,B1l_) }
        { bf16x8 Ah_,Al_; LDA2(x2s1,1,Ah_,Al_) MF3(f2[2],Ah_,Al_,B0h_,B0l_) MF3(f2[3],Ah_,Al_,B1h_,B1l_) }
        { bf16x8 Ah_,Al_; LDA2(x2s1,2,Ah_,Al_) MF3(f2[4],Ah_,Al_,B0h_,B0l_) MF3(f2[5],Ah_,Al_,B1h_,B1l_) }
        { bf16x8 Ah_,Al_; LDA2(x2s1,3,Ah_,Al_) MF3(f2[6],Ah_,Al_,B0h_,B0l_) MF3(f2[7],Ah_,Al_,B1h_,B1l_) }
    }

    // ---- bn2 + mish in C layout ----
    float s2a = fold[16+c0], t2a = fold[48+c0];
    float s2b = fold[32+c0], t2b = fold[64+c0];
#define MSH4(s, SS, TT) { f2[s].x=mishf(f2[s].x*(SS)+(TT)); f2[s].y=mishf(f2[s].y*(SS)+(TT)); \
                          f2[s].z=mishf(f2[s].z*(SS)+(TT)); f2[s].w=mishf(f2[s].w*(SS)+(TT)); }
    MSH4(0,s2a,t2a) MSH4(1,s2b,t2b) MSH4(2,s2a,t2a) MSH4(3,s2b,t2b)
    MSH4(4,s2a,t2a) MSH4(5,s2b,t2b) MSH4(6,s2a,t2a) MSH4(7,s2b,t2b)
#undef MSH4

    // ---- pool over UNMASKED rows (reference pools pre-mask), col-group butterfly ----
#define MX4(V) fmaxf(fmaxf((V).x,(V).y), fmaxf((V).z,(V).w))
    float aggA0 = fmaxf(MX4(f2[0]), MX4(f2[2]));
    float aggA1 = fmaxf(MX4(f2[1]), MX4(f2[3]));
    float aggB0 = fmaxf(MX4(f2[4]), MX4(f2[6]));
    float aggB1 = fmaxf(MX4(f2[5]), MX4(f2[7]));
#undef MX4
#define REDQ(p) p = fmaxf(p, __shfl_xor(p, 16)); p = fmaxf(p, __shfl_xor(p, 32));
    REDQ(aggA0) REDQ(aggA1) REDQ(aggB0) REDQ(aggB1)
#undef REDQ
    if (lane < 16) {
        aggL[c0]    = aggA0;  aggL[16+c0] = aggA1;
        aggL[32+c0] = aggB0;  aggL[48+c0] = aggB1;
    }
    uint sgA0 = splitbf(aggA0), sgA1 = splitbf(aggA1);
    uint sgB0 = splitbf(aggB0), sgB1 = splitbf(aggB1);

    // ---- stage masked x2 into chunk0 (p half) + chunk1 (agg half), [row][ch] ----
#define ST2(mt, NVV, SG0, SG1) { \
    int rt_ = quad*4 + 16*((mt)&1); \
    int gr_ = (quad*4 + 16*(mt))*33; \
    float m0_=(rt_+0<(NVV))?1.f:0.f, m1_=(rt_+1<(NVV))?1.f:0.f; \
    float m2_=(rt_+2<(NVV))?1.f:0.f, m3_=(rt_+3<(NVV))?1.f:0.f; \
    f32x4 a_ = f2[(mt)*2], b_ = f2[(mt)*2+1]; \
    x2s[gr_    + c0] = splitbf(a_.x*m0_);  x2s[gr_    + c0+16] = splitbf(b_.x*m0_); \
    x2s[gr_+33 + c0] = splitbf(a_.y*m1_);  x2s[gr_+33 + c0+16] = splitbf(b_.y*m1_); \
    x2s[gr_+66 + c0] = splitbf(a_.z*m2_);  x2s[gr_+66 + c0+16] = splitbf(b_.z*m2_); \
    x2s[gr_+99 + c0] = splitbf(a_.w*m3_);  x2s[gr_+99 + c0+16] = splitbf(b_.w*m3_); \
    x2s1[gr_    + c0] = (m0_!=0.f)?(SG0):0u;  x2s1[gr_    + c0+16] = (m0_!=0.f)?(SG1):0u; \
    x2s1[gr_+33 + c0] = (m1_!=0.f)?(SG0):0u;  x2s1[gr_+33 + c0+16] = (m1_!=0.f)?(SG1):0u; \
    x2s1[gr_+66 + c0] = (m2_!=0.f)?(SG0):0u;  x2s1[gr_+66 + c0+16] = (m2_!=0.f)?(SG1):0u; \
    x2s1[gr_+99 + c0] = (m3_!=0.f)?(SG0):0u;  x2s1[gr_+99 + c0+16] = (m3_!=0.f)?(SG1):0u; }
    ST2(0, nA, sgA0, sgA1)
    ST2(2, nB, sgB0, sgB1)
    if (!skipA) { ST2(1, nA, sgA0, sgA1) }
    if (!skipB) { ST2(3, nB, sgB0, sgB1) }
#undef ST2

    // ================= fe3 onward: byte-identical to round 4 =================

    // ---- fe3: up to 96 MFMAs over K=64 (two 32-K sets), dead tiles skipped ----
    f32x4 e[16];
#define EIN(i) e[i] = (f32x4){0.f,0.f,0.f,0.f};
    REP16_0(EIN)
#undef EIN
    {
        const uint4* bh3 = (const uint4*)w3fh + lane;
        const uint4* bl3 = (const uint4*)w3fl + lane;
        DOSET(x2s, bh3, bl3, e, skipA, skipB)
    }
    {
        const uint4* bh3 = (const uint4*)w3fh + 256 + lane;
        const uint4* bl3 = (const uint4*)w3fl + 256 + lane;
        const uint* sp = x2s1;
        DOSET(sp, bh3, bl3, e, skipA, skipB)
    }

    // ---- fe3 epilogue (bn+mish+split, C-layout) interleaved with fe4 MFMA ----
    uint* x3st = x2s1;   // agg chunk reused as x3 staging
    f32x4 d[16];
#define DIN(i) d[i] = (f32x4){0.f,0.f,0.f,0.f};
    REP16_0(DIN)
#undef DIN

#define POST(TI, mt, nt) { \
    float s_ = fold[80 + c0 + 16*(nt)], tb_ = fold[144 + c0 + 16*(nt)]; \
    int col_ = c0 + 16*((nt)&1); \
    int rowb_ = quad*4 + 16*(mt); \
    x3st[(rowb_+0)*33 + col_] = splitbf(mishf(e[TI].x * s_ + tb_)); \
    x3st[(rowb_+1)*33 + col_] = splitbf(mishf(e[TI].y * s_ + tb_)); \
    x3st[(rowb_+2)*33 + col_] = splitbf(mishf(e[TI].z * s_ + tb_)); \
    x3st[(rowb_+3)*33 + col_] = splitbf(mishf(e[TI].w * s_ + tb_)); }

    { // output chunk 0: fe3 outputs 0..31 (nt 0,1)
        POST(0,0,0)  POST(1,0,1)
        POST(8,2,0)  POST(9,2,1)
        if (!skipA) { POST(4,1,0)  POST(5,1,1) }
        if (!skipB) { POST(12,3,0) POST(13,3,1) }
        const uint4* bh4 = (const uint4*)w4fh + lane;
        const uint4* bl4 = (const uint4*)w4fl + lane;
        DOSET(x3st, bh4, bl4, d, skipA, skipB)
    }
    { // output chunk 1: fe3 outputs 32..63 (nt 2,3)
        POST(2,0,2)  POST(3,0,3)
        POST(10,2,2) POST(11,2,3)
        if (!skipA) { POST(6,1,2)  POST(7,1,3) }
        if (!skipB) { POST(14,3,2) POST(15,3,3) }
        const uint4* bh4 = (const uint4*)w4fh + 256 + lane;
        const uint4* bl4 = (const uint4*)w4fl + 256 + lane;
        DOSET(x3st, bh4, bl4, d, skipA, skipB)
    }
#undef POST

    // ---- bn4 + mish + residual + pool in C layout ----
    float s0f = fold[208+c0],    t0f = fold[272+c0];
    float s1f = fold[208+16+c0], t1f = fold[272+16+c0];
    float s2f = fold[208+32+c0], t2f = fold[272+32+c0];
    float s3f = fold[208+48+c0], t3f = fold[272+48+c0];
    float rA2 = aggL[c0],      rA3 = aggL[16+c0];
    float rB2 = aggL[32+c0],   rB3 = aggL[48+c0];
    // Skipped tiles' rows would contribute exactly 0 to the pool -> seed 0.
    float piA = skipA ? 0.f : -3.4e38f;
    float piB = skipB ? 0.f : -3.4e38f;
    float pA0=piA, pA1=piA, pA2=piA, pA3=piA;
    float pB0=piB, pB1=piB, pB2=piB, pB3=piB;

#define RECON(u) (__uint_as_float((u)<<16) + __uint_as_float((u) & 0xFFFF0000u))
#define FTP(D, mt, nt, SS, TT, PV) { \
    int nv = ((mt) >> 1) ? nB : nA; \
    int rf = quad*4 + 16*(mt); \
    int rt = quad*4 + 16*((mt)&1); \
    int cb = c0 + 16*(nt); \
    float m0=(rt+0<nv)?1.f:0.f, m1=(rt+1<nv)?1.f:0.f, m2=(rt+2<nv)?1.f:0.f, m3=(rt+3<nv)?1.f:0.f; \
    uint ua_ = x2s[(rf+0)*33 + cb], ub_ = x2s[(rf+1)*33 + cb]; \
    uint uc_ = x2s[(rf+2)*33 + cb], ud_ = x2s[(rf+3)*33 + cb]; \
    float y0 = mishf(D.x*SS + TT)*m0 + RECON(ua_); \
    float y1 = mishf(D.y*SS + TT)*m1 + RECON(ub_); \
    float y2 = mishf(D.z*SS + TT)*m2 + RECON(uc_); \
    float y3 = mishf(D.w*SS + TT)*m3 + RECON(ud_); \
    PV = fmaxf(PV, fmaxf(fmaxf(y0,y1), fmaxf(y2,y3))); }

#define FTA(D, mt, nt, SS, TT, AG, PV) { \
    int nv = ((mt) >> 1) ? nB : nA; \
    int rt = quad*4 + 16*((mt)&1); \
    float m0=(rt+0<nv)?1.f:0.f, m1=(rt+1<nv)?1.f:0.f, m2=(rt+2<nv)?1.f:0.f, m3=(rt+3<nv)?1.f:0.f; \
    float y0 = (mishf(D.x*SS + TT) + AG)*m0; \
    float y1 = (mishf(D.y*SS + TT) + AG)*m1; \
    float y2 = (mishf(D.z*SS + TT) + AG)*m2; \
    float y3 = (mishf(D.w*SS + TT) + AG)*m3; \
    PV = fmaxf(PV, fmaxf(fmaxf(y0,y1), fmaxf(y2,y3))); }

    FTP(d[0], 0, 0, s0f, t0f, pA0)  FTP(d[1], 0, 1, s1f, t1f, pA1)
    FTA(d[2], 0, 2, s2f, t2f, rA2, pA2)  FTA(d[3], 0, 3, s3f, t3f, rA3, pA3)
    if (!skipA) {
        FTP(d[4], 1, 0, s0f, t0f, pA0)  FTP(d[5], 1, 1, s1f, t1f, pA1)
        FTA(d[6], 1, 2, s2f, t2f, rA2, pA2)  FTA(d[7], 1, 3, s3f, t3f, rA3, pA3)
    }
    FTP(d[8], 2, 0, s0f, t0f, pB0)  FTP(d[9], 2, 1, s1f, t1f, pB1)
    FTA(d[10], 2, 2, s2f, t2f, rB2, pB2)  FTA(d[11], 2, 3, s3f, t3f, rB3, pB3)
    if (!skipB) {
        FTP(d[12], 3, 0, s0f, t0f, pB0)  FTP(d[13], 3, 1, s1f, t1f, pB1)
        FTA(d[14], 3, 2, s2f, t2f, rB2, pB2)  FTA(d[15], 3, 3, s3f, t3f, rB3, pB3)
    }
#undef FTP
#undef FTA
#undef RECON

#define RED(p) p = fmaxf(p, __shfl_xor(p, 16)); p = fmaxf(p, __shfl_xor(p, 32));
    RED(pA0) RED(pA1) RED(pA2) RED(pA3) RED(pB0) RED(pB1) RED(pB2) RED(pB3)
#undef RED

    if (quad == 0) {
        float* vwA = voxelwise + vA*64;
        vwA[c0] = pA0; vwA[c0+16] = pA1; vwA[c0+32] = pA2; vwA[c0+48] = pA3;
        float* vwB = voxelwise + (vA+1)*64;
        vwB[c0] = pB0; vwB[c0+16] = pB1; vwB[c0+32] = pB2; vwB[c0+48] = pB3;
    }

    if (t == 0) {
        int cell = coors[v*2] * BEVW + coors[v*2+1];
        int pos = atomicAdd(&cnt[cell], 1);
        if (pos < 16) list[cell*16 + pos] = v;
        if (pos == 0) { int k = atomicAdd(nact, 1); act[k] = cell; }
    }
}

// ---------------- BFE front: 1 wave = 1 cell; records idx[cell]=aidx+1 ----------------
__global__ __launch_bounds__(256) void bfe_front(
    const int* __restrict__ nact, const int* __restrict__ act,
    const int* __restrict__ cnt, const int* __restrict__ list,
    const float* __restrict__ voxelwise,
    const float* __restrict__ W1g, const float* __restrict__ W2g,
    const float* __restrict__ fold, float* __restrict__ x17g,
    int* __restrict__ idx)
{
    int n_act = *nact;
    int aidx = blockIdx.x * 4 + (threadIdx.x >> 6);
    if (aidx >= n_act) return;

    int lane = threadIdx.x & 63;
    int g = lane >> 2, ii = lane & 3;
    int cell = act[aidx];
    int numv = min(cnt[cell], 16);
    if (lane == 0) idx[cell] = aidx + 1;

    int myidx = (lane < numv) ? list[cell*16 + lane] : (0x40000000 + lane);
    int rank = 0;
    for (int j = 0; j < numv; j++) { int vj = __shfl(myidx, j); rank += (vj < myidx) ? 1 : 0; }
    if (lane >= numv) rank = lane;
    int sorted = __builtin_amdgcn_ds_permute(rank << 2, myidx);

#define YD(q) float y_##q = 0.f;
    REP16_0(YD)
#undef YD
    for (int p = 0; p < numv; p++) {
        int sv = __shfl(sorted, p);
        float val = voxelwise[sv*64 + lane];
        const float* w = W1g + g*256 + p;
#define BF1(q) y_##q += val * w[(q)*16];
        REP16_0(BF1)
#undef BF1
    }
#define BN1(q) { float yy = y_##q * fold[592 + g*16 + (q)] + fold[848 + g*16 + (q)]; \
    yy = mishf(yy); y_##q = ((q) < numv) ? yy : 0.f; }
    REP16_0(BN1)
#undef BN1

    float z0 = 0.f, z1 = 0.f;
#define BF2(p) z0 += y_##p * W2g[g*32 + (p)]; z1 += y_##p * W2g[g*32 + 16 + (p)];
    REP16_0(BF2)
#undef BF2
    z0 = mishf(z0 * fold[1104 + g*2 + 0] + fold[1136 + g*2 + 0]);
    z1 = mishf(z1 * fold[1104 + g*2 + 1] + fold[1136 + g*2 + 1]);

    int k0 = ii*32 + g*2;
    *(float2*)(x17g + aidx*128 + k0) = make_float2(z0, z1);
}

// ---------------- bfe3 fused: x19 compactly back into x17g ----------------
__global__ __launch_bounds__(512, 4) void bfe3_fused(
    const int* __restrict__ nactp,
    const float* __restrict__ W3, const float* __restrict__ fold,
    float* __restrict__ x17g)
{
    __shared__ float XL[64*128];
    int tid = threadIdx.x;
    int n_act = *nactp;
    int cb = blockIdx.x * 64;

    for (int i = tid; i < 64*32; i += 512) {
        int c = i >> 5, kc = i & 31;
        float4 val = (cb + c < n_act) ? ((const float4*)x17g)[(size_t)(cb+c)*32 + kc]
                                      : make_float4(0.f,0.f,0.f,0.f);
        ((float4*)XL)[c*32 + (kc ^ (c & 31))] = val;
    }
    __syncthreads();

    int wv = __builtin_amdgcn_readfirstlane(tid >> 6);
    int c  = tid & 63;
    int ob = wv * 16;
    int cswz = c & 31;
    const float4* xrow = (const float4*)XL + c*32;
    const float4* W4p = (const float4*)W3;

#define DECLB(q) f32x2 ap_##q = {0.f, 0.f};
#define ACCB(q) { const f32x2* wp_ = (const f32x2*)(W4p + (ob+(q))*32 + kc); \
    ap_##q += xv01 * wp_[0]; ap_##q += xv23 * wp_[1]; }
#define ACTB(q) float a_##q; { float yy = (ap_##q.x + ap_##q.y) * fold[336+ob+(q)] + fold[464+ob+(q)]; a_##q = mishf(yy); }
    {
        REP16_0(DECLB)
        for (int kc = 0; kc < 32; kc++) {
            float4 xv = xrow[kc ^ cswz];
            f32x2 xv01 = {xv.x, xv.y}, xv23 = {xv.z, xv.w};
            REP16_0(ACCB)
        }
        REP16_0(ACTB)
        __syncthreads();
        ((float4*)XL)[c*32 + ((wv*4 + 0) ^ cswz)] = make_float4(a_0,  a_1,  a_2,  a_3);
        ((float4*)XL)[c*32 + ((wv*4 + 1) ^ cswz)] = make_float4(a_4,  a_5,  a_6,  a_7);
        ((float4*)XL)[c*32 + ((wv*4 + 2) ^ cswz)] = make_float4(a_8,  a_9,  a_10, a_11);
        ((float4*)XL)[c*32 + ((wv*4 + 3) ^ cswz)] = make_float4(a_12, a_13, a_14, a_15);
    }
    __syncthreads();

    {
        const float4* yrow = (const float4*)XL + c*32;
        REP16_0(DECLB)
        for (int kc = 0; kc < 32; kc++) {
            float4 xv = yrow[kc ^ cswz];
            f32x2 xv01 = {xv.x, xv.y}, xv23 = {xv.z, xv.w};
            REP16_0(ACCB)
        }
        REP16_0(ACTB)
        float4* dst = (float4*)(x17g + (size_t)(cb + c)*128 + ob);
        dst[0] = make_float4(a_0,  a_1,  a_2,  a_3);
        dst[1] = make_float4(a_4,  a_5,  a_6,  a_7);
        dst[2] = make_float4(a_8,  a_9,  a_10, a_11);
        dst[3] = make_float4(a_12, a_13, a_14, a_15);
    }
#undef DECLB
#undef ACCB
#undef ACTB
}

// ---------------- bev_write: tiled transpose-scatter (replaces out memset) ----------------
__global__ __launch_bounds__(512, 2) void bev_write(
    const int* __restrict__ idx, const float* __restrict__ x19c,
    float* __restrict__ out)
{
    __shared__ float XT[128*65];
    int bid = blockIdx.x;
    int cx = bid % BEVW;
    int cy0 = (bid / BEVW) << 6;
    int tid = threadIdx.x;

    int cell_l = tid >> 3;
    int chq = (tid & 7) << 4;
    int cy = cy0 + cell_l;
    float4 v0 = make_float4(0.f,0.f,0.f,0.f), v1 = v0, v2 = v0, v3 = v0;
    if (cy < BEVH) {
        int ai = idx[cy*BEVW + cx] - 1;
        if (ai >= 0) {
            const float4* src = (const float4*)(x19c + (size_t)ai*128 + chq);
            v0 = src[0]; v1 = src[1]; v2 = src[2]; v3 = src[3];
        }
    }
    float* d = XT + chq*65 + cell_l;
    d[0*65]=v0.x;  d[1*65]=v0.y;  d[2*65]=v0.z;  d[3*65]=v0.w;
    d[4*65]=v1.x;  d[5*65]=v1.y;  d[6*65]=v1.z;  d[7*65]=v1.w;
    d[8*65]=v2.x;  d[9*65]=v2.y;  d[10*65]=v2.z; d[11*65]=v2.w;
    d[12*65]=v3.x; d[13*65]=v3.y; d[14*65]=v3.z; d[15*65]=v3.w;
    __syncthreads();

    int wv2 = tid >> 6, lane = tid & 63;
    int cyw = cy0 + lane;
    if (cyw < BEVH) {
        float* op = out + cx*BEVH + cyw;
#pragma unroll
        for (int k = 0; k < 16; k++) {
            int c = (wv2 << 4) + k;
            op[(size_t)c*NCELL] = XT[c*65 + lane];
        }
    }
}

extern "C" void kernel_launch(void* const* d_in, const int* in_sizes, int n_in,
                              void* d_out, int out_size, void* d_ws, size_t ws_size,
                              hipStream_t stream) {
    const float* features = (const float*)d_in[0];
    const int*   coors    = (const int*)d_in[1];
    const int*   num_vox  = (const int*)d_in[2];
    const float* vfe1_W   = (const float*)d_in[3];
    const float* vfe1_bn  = (const float*)d_in[4];
    const float* vfe2_W   = (const float*)d_in[5];
    const float* vfe2_bn  = (const float*)d_in[6];
    const float* vfe3_W   = (const float*)d_in[7];
    const float* vfe3_bn  = (const float*)d_in[8];
    const float* vfe4_W   = (const float*)d_in[9];
    const float* vfe4_bn  = (const float*)d_in[10];
    const float* bfe1_W   = (const float*)d_in[11];
    const float* bfe1_bn  = (const float*)d_in[12];
    const float* bfe2_W   = (const float*)d_in[13];
    const float* bfe2_bn  = (const float*)d_in[14];
    const float* bfe3_W   = (const float*)d_in[15];
    const float* bfe3_bn  = (const float*)d_in[16];
    float* out = (float*)d_out;

    char* ws = (char*)d_ws;
    int*    nact      = (int*)ws;                       // zeroed
    int*    cnt       = (int*)(ws + 256);               // zeroed
    int*    idx       = (int*)(ws + 857344);            // zeroed (aidx+1 encoding)
    int*    list      = (int*)(ws + 1714432);
    float*  voxelwise = (float*)(ws + 15427840);
    int*    act       = (int*)(ws + 25667840);
    float*  x17g      = (float*)(ws + 25827840);
    float*  fold      = (float*)(ws + 46307840);
    ushort* w4fh      = (ushort*)(ws + 46312512);
    ushort* w4fl      = (ushort*)(ws + 46320704);
    ushort* w3fh      = (ushort*)(ws + 46328896);
    ushort* w3fl      = (ushort*)(ws + 46337088);
    ushort* w2fh      = (ushort*)(ws + 46345280);
    ushort* w2fl      = (ushort*)(ws + 46347328);

    (void)hipMemsetAsync(ws, 0, 1714432, stream);   // nact + cnt + idx in one shot

    setup_kernel<<<1, 256, 0, stream>>>(vfe1_bn, vfe2_bn, vfe3_bn, vfe4_bn,
                                        bfe1_bn, bfe2_bn, bfe3_bn, vfe4_W, vfe3_W, vfe2_W,
                                        fold, w4fh, w4fl, w3fh, w3fl, w2fh, w2fl);
    vfe_kernel<<<NVOX/2, 64, 0, stream>>>(features, coors, num_vox,
                                          vfe1_W, w2fh, w2fl, w3fh, w3fl, w4fh, w4fl, fold,
                                          voxelwise, cnt, list, nact, act);
    bfe_front<<<NVOX/4, 256, 0, stream>>>(nact, act, cnt, list, voxelwise,
                                          bfe1_W, bfe2_W, fold, x17g, idx);
    bfe3_fused<<<(NVOX+63)/64, 512, 0, stream>>>(nact, bfe3_W, fold, x17g);
    bev_write<<<BEVW*8, 512, 0, stream>>>(idx, x17g, out);
}

// Round 6
// 507.480 us; speedup vs baseline: 1.3693x; 1.0028x over previous
//
#include <hip/hip_runtime.h>

#define BEVW 432
#define BEVH 496
#define NCELL (BEVW*BEVH)      // 214272
#define NVOX  40000
#define EPSB  1e-5f

typedef float f32x2 __attribute__((ext_vector_type(2)));
typedef float f32x4 __attribute__((ext_vector_type(4)));
typedef unsigned int u32x4 __attribute__((ext_vector_type(4)));
typedef short bf16x8 __attribute__((ext_vector_type(8)));

// ---- repeat macros ----
#define REP8_0(M)  M(0) M(1) M(2) M(3) M(4) M(5) M(6) M(7)
#define REP8_8(M)  M(8) M(9) M(10) M(11) M(12) M(13) M(14) M(15)
#define REP16_0(M)  REP8_0(M)  REP8_8(M)

// ---------------- workspace layout (bytes) ----------------
// 0        : int nact (zeroed)
// 256      : int cnt[NCELL]  (zeroed)            -> 857344
// 857344   : int idx[NCELL]  (zeroed; aidx+1)    -> 1714432
// 1714432  : int list[NCELL*16]                  -> 15427840
// 15427840 : float voxelwise[NVOX*64]            -> 25667840
// 25667840 : int act[NVOX]                       -> 25827840
// 25827840 : float x17g[NVOX*128] (x17 then x19) -> 46307840
// 46307840 : float fold[1168]
// 46312512 : w4fh | 46320704: w4fl | 46328896: w3fh | 46337088: w3fl
// 46345280 : w2fh[1024] | 46347328 : w2fl[1024]

__device__ __forceinline__ float mishf(float y) {
    float e = __expf(fminf(y, 40.f));
    float n = e * (e + 2.f);
    return y * n * __builtin_amdgcn_rcpf(n + 2.f);
}

template <int CTRL>
__device__ __forceinline__ float dppmaxf(float a) {
    int p = __builtin_amdgcn_update_dpp(0, __float_as_int(a), CTRL, 0xF, 0xF, true);
    return fmaxf(a, __int_as_float(p));
}
#define WMAX32(a) { \
    a = dppmaxf<0xB1>(a); \
    a = dppmaxf<0x4E>(a); \
    a = dppmaxf<0x141>(a); \
    a = dppmaxf<0x140>(a); \
    a = fmaxf(a, __int_as_float(__builtin_amdgcn_ds_swizzle(__float_as_int(a), 0x401F))); }

__device__ __forceinline__ bf16x8 mkbf8(uint a, uint b, uint c, uint d) {
    u32x4 t = {a, b, c, d};
    return __builtin_bit_cast(bf16x8, t);
}

// split fp32 -> (hi bf16 | lo bf16 << 16). Hi = TRUNCATION (1 op); lo = x - hi is
// then exact in fp32, RNE'd to bf16. Combined representation err ~2^-17 rel.
__device__ __forceinline__ uint splitbf(float x) {
    uint rh = __float_as_uint(x) & 0xFFFF0000u;
    float lof = x - __uint_as_float(rh);
    uint ul = __float_as_uint(lof);
    uint rl = (ul + 0x7FFFu + ((ul >> 16) & 1u)) >> 16;
    return (rh >> 16) | (rl << 16);
}

// fold layout: vfe1 s@0 t@8 | vfe2 s@16 t@48 | vfe3 s@80 t@144 | vfe4 s@208 t@272
// bfe3 s@336 t@464 | bfe1 s@592 t@848 | bfe2 s@1104 t@1136
__global__ __launch_bounds__(256) void setup_kernel(
    const float* __restrict__ vbn1, const float* __restrict__ vbn2,
    const float* __restrict__ vbn3, const float* __restrict__ vbn4,
    const float* __restrict__ bbn1, const float* __restrict__ bbn2,
    const float* __restrict__ bbn3, const float* __restrict__ W4,
    const float* __restrict__ W3g, const float* __restrict__ W2g,
    float* __restrict__ fold, ushort* __restrict__ w4fh, ushort* __restrict__ w4fl,
    ushort* __restrict__ w3fh, ushort* __restrict__ w3fl,
    ushort* __restrict__ w2fh, ushort* __restrict__ w2fl)
{
    int tid = threadIdx.x;
    if (tid < 8)  { float s = vbn1[tid]/sqrtf(vbn1[24+tid]+EPSB);  fold[tid]      = s; fold[8+tid]   = vbn1[8+tid]  - vbn1[16+tid]*s; }
    if (tid < 32) { float s = vbn2[tid]/sqrtf(vbn2[96+tid]+EPSB);  fold[16+tid]   = s; fold[48+tid]  = vbn2[32+tid] - vbn2[64+tid]*s; }
    if (tid < 64) { float s = vbn3[tid]/sqrtf(vbn3[192+tid]+EPSB); fold[80+tid]   = s; fold[144+tid] = vbn3[64+tid] - vbn3[128+tid]*s; }
    if (tid < 64) { float s = vbn4[tid]/sqrtf(vbn4[192+tid]+EPSB); fold[208+tid]  = s; fold[272+tid] = vbn4[64+tid] - vbn4[128+tid]*s; }
    if (tid < 128){ float s = bbn3[tid]/sqrtf(bbn3[384+tid]+EPSB); fold[336+tid]  = s; fold[464+tid] = bbn3[128+tid]- bbn3[256+tid]*s; }
    { int g = tid >> 4, q = tid & 15;
      const float* b = bbn1 + g*64;
      float s = b[q]/sqrtf(b[48+q]+EPSB);
      fold[592+tid] = s; fold[848+tid] = b[16+q] - b[32+q]*s; }
    if (tid < 32) { int g = tid >> 1, c = tid & 1;
      const float* b = bbn2 + g*8;
      float s = b[c]/sqrtf(b[6+c]+EPSB);
      fold[1104+tid] = s; fold[1136+tid] = b[2+c] - b[4+c]*s; }

    // B-fragments (B[k][n] = W[n][k]) split bf16 hi/lo, for W4^T and W3^T.
    // frag idx = ((kc*4 + nt)*64 + lane)*8 + j ; n = (lane&15)+16nt ; k = kc*32 + (lane>>4)*8 + j
    for (int i = tid; i < 4096; i += 256) {
        int j = i & 7, ln = (i >> 3) & 63, nt = (i >> 9) & 3, kc = i >> 11;
        int n = (ln & 15) + nt*16;
        int k = kc*32 + (ln >> 4)*8 + j;
        {
            float val = W4[n*64 + k];
            uint u = splitbf(val);
            w4fh[i] = (ushort)(u & 0xFFFFu);
            w4fl[i] = (ushort)(u >> 16);
        }
        {
            float val = W3g[n*64 + k];
            uint u = splitbf(val);
            w3fh[i] = (ushort)(u & 0xFFFFu);
            w3fl[i] = (ushort)(u >> 16);
        }
    }

    // W2 B-fragments: K=16 padded to 32 with ZERO weights (k>=16 -> 0), N=32.
    // frag idx = (nt*64 + lane)*8 + j ; n = (lane&15)+16nt ; k = (lane>>4)*8 + j
    for (int i = tid; i < 1024; i += 256) {
        int j = i & 7, ln = (i >> 3) & 63, nt = (i >> 9) & 1;
        int n = (ln & 15) + nt*16;
        int k = (ln >> 4)*8 + j;
        float val = (k < 16) ? W2g[n*16 + k] : 0.f;
        uint u = splitbf(val);
        w2fh[i] = (ushort)(u & 0xFFFFu);
        w2fl[i] = (ushort)(u >> 16);
    }
}

#define MF3(D, AH, AL, BH, BL) \
    D = __builtin_amdgcn_mfma_f32_16x16x32_bf16(AL, BH, D, 0, 0, 0); \
    D = __builtin_amdgcn_mfma_f32_16x16x32_bf16(AH, BL, D, 0, 0, 0); \
    D = __builtin_amdgcn_mfma_f32_16x16x32_bf16(AH, BH, D, 0, 0, 0);

// Load one A-tile (16 rows) from LDS rows (stride 33) and pack hi/lo bf16 frags.
#define LDA(SRCP, mt, AH, AL) { \
    const uint* ap_ = (SRCP) + ((lane & 15) + 16*(mt))*33 + quad*8; \
    uint u0 = ap_[0], u1 = ap_[1], u2 = ap_[2], u3 = ap_[3]; \
    uint u4 = ap_[4], u5 = ap_[5], u6 = ap_[6], u7 = ap_[7]; \
    AH = mkbf8(__builtin_amdgcn_perm(u1,u0,0x05040100), __builtin_amdgcn_perm(u3,u2,0x05040100), \
               __builtin_amdgcn_perm(u5,u4,0x05040100), __builtin_amdgcn_perm(u7,u6,0x05040100)); \
    AL = mkbf8(__builtin_amdgcn_perm(u1,u0,0x07060302), __builtin_amdgcn_perm(u3,u2,0x07060302), \
               __builtin_amdgcn_perm(u5,u4,0x07060302), __builtin_amdgcn_perm(u7,u6,0x07060302)); }

// fe2 A-tile: K=16 real data in cols 0-15. Quads 2,3 (k 16-31) RE-READ cols 0-15
// ((quad&1) addressing) so A stays finite; their B weights are exactly 0.
#define LDA2(SRCP, mt, AH, AL) { \
    const uint* ap_ = (SRCP) + ((lane & 15) + 16*(mt))*33 + (quad & 1)*8; \
    uint u0 = ap_[0], u1 = ap_[1], u2 = ap_[2], u3 = ap_[3]; \
    uint u4 = ap_[4], u5 = ap_[5], u6 = ap_[6], u7 = ap_[7]; \
    AH = mkbf8(__builtin_amdgcn_perm(u1,u0,0x05040100), __builtin_amdgcn_perm(u3,u2,0x05040100), \
               __builtin_amdgcn_perm(u5,u4,0x05040100), __builtin_amdgcn_perm(u7,u6,0x05040100)); \
    AL = mkbf8(__builtin_amdgcn_perm(u1,u0,0x07060302), __builtin_amdgcn_perm(u3,u2,0x07060302), \
               __builtin_amdgcn_perm(u5,u4,0x07060302), __builtin_amdgcn_perm(u7,u6,0x07060302)); }

// Load a 4-pair (h/l) B-fragment batch into a register array (8 bf16x8 = 32 VGPR).
// Issued as 8 independent global_load_dwordx4 — place well before consumption.
#define LDB8(ARR, BHP, BLP) { \
    uint4 h0_=(BHP)[0], l0_=(BLP)[0], h1_=(BHP)[64], l1_=(BLP)[64]; \
    uint4 h2_=(BHP)[128], l2_=(BLP)[128], h3_=(BHP)[192], l3_=(BLP)[192]; \
    ARR[0]=mkbf8(h0_.x,h0_.y,h0_.z,h0_.w); ARR[1]=mkbf8(l0_.x,l0_.y,l0_.z,l0_.w); \
    ARR[2]=mkbf8(h1_.x,h1_.y,h1_.z,h1_.w); ARR[3]=mkbf8(l1_.x,l1_.y,l1_.z,l1_.w); \
    ARR[4]=mkbf8(h2_.x,h2_.y,h2_.z,h2_.w); ARR[5]=mkbf8(l2_.x,l2_.y,l2_.z,l2_.w); \
    ARR[6]=mkbf8(h3_.x,h3_.y,h3_.z,h3_.w); ARR[7]=mkbf8(l3_.x,l3_.y,l3_.z,l3_.w); }

// One A-tile vs all 4 preloaded B pairs: 12 MFMAs, 4 independent chains.
#define TILE4A(SRCP, mt, BA, D0, D1, D2, D3) { \
    bf16x8 Ah_, Al_; LDA(SRCP, mt, Ah_, Al_) \
    MF3(D0, Ah_, Al_, BA[0], BA[1]) MF3(D1, Ah_, Al_, BA[2], BA[3]) \
    MF3(D2, Ah_, Al_, BA[4], BA[5]) MF3(D3, Ah_, Al_, BA[6], BA[7]) }

// Full 64x64 += 64-rows x 32-K set with wave-uniform dead-tile skip. B operands
// come from a preloaded register array. Per-accumulator MFMA chain order is
// IDENTICAL to rounds 3-5 (bit-identical results).
#define DOSETA(SRCP, BA, ACC, SKA, SKB) { \
    TILE4A(SRCP, 0, BA, ACC[0], ACC[1], ACC[2], ACC[3]) \
    TILE4A(SRCP, 2, BA, ACC[8], ACC[9], ACC[10], ACC[11]) \
    if (!(SKA)) { TILE4A(SRCP, 1, BA, ACC[4], ACC[5], ACC[6], ACC[7]) } \
    if (!(SKB)) { TILE4A(SRCP, 3, BA, ACC[12], ACC[13], ACC[14], ACC[15]) } }

// ---------------- VFE: single-wave blocks (2 voxels/wave), fe2+fe3+fe4 on MFMA ----------------
// R1: occupancy restructure regressed -> per-wave work. R3: B-hoist 341->289.
// R4: dead-tile skip ->262. R5: fe2 on MFMA ->254 (VALU 51->42: now STALL-bound).
// R6: register math shows we're pinned at 2 waves/SIMD by the unified VGPR+AGPR
// budget (e+d acc = 128 + ~80 arch ~ 208); ~48 regs spare. Spend 32 on a
// double-buffered B-fragment pipeline (BA/BB, 8 bf16x8 each): every MFMA phase's
// 8x16B L1 loads issue 300-500 cycles before first use, hidden under compute.
// Also deleted the aggL LDS round-trip (post-butterfly registers already hold it).
__global__ __launch_bounds__(64, 3) void vfe_kernel(
    const float* __restrict__ feat, const int* __restrict__ coors,
    const int* __restrict__ nvx,
    const float* __restrict__ W1,
    const ushort* __restrict__ w2fh, const ushort* __restrict__ w2fl,
    const ushort* __restrict__ w3fh, const ushort* __restrict__ w3fl,
    const ushort* __restrict__ w4fh, const ushort* __restrict__ w4fl,
    const float* __restrict__ fold,
    float* __restrict__ voxelwise, int* __restrict__ cnt,
    int* __restrict__ list, int* __restrict__ nact, int* __restrict__ act)
{
    __shared__ char ldsbuf[16896];   // x2s[2][64][33] u32 (aggL eliminated)
    int tid = threadIdx.x;
    int lane = tid;
    int quad = lane >> 4;
    int c0 = lane & 15;
    int v = blockIdx.x * 2 + (tid >> 5);
    int vA = blockIdx.x * 2;
    int t = tid & 31;
    uint*  x2s  = (uint*)ldsbuf;
    uint*  x2s1 = x2s + 2112;        // chunk1

    // ---- early independent loads: features + fe2 B-fragments ----
    const float* fp = feat + (v*32 + t)*8;
    float4 fa = *(const float4*)(fp);
    float4 fb = *(const float4*)(fp+4);
    int numv = nvx[v];
    bf16x8 Bw2[4];
    {
        const uint4* bh2 = (const uint4*)w2fh + lane;
        const uint4* bl2 = (const uint4*)w2fl + lane;
        uint4 h0_=bh2[0], l0_=bl2[0], h1_=bh2[64], l1_=bl2[64];
        Bw2[0]=mkbf8(h0_.x,h0_.y,h0_.z,h0_.w); Bw2[1]=mkbf8(l0_.x,l0_.y,l0_.z,l0_.w);
        Bw2[2]=mkbf8(h1_.x,h1_.y,h1_.z,h1_.w); Bw2[3]=mkbf8(l1_.x,l1_.y,l1_.z,l1_.w);
    }

    // ---- fe1 (8->8) + pool (VALU; lane owns row t of its voxel) ----
#define D1(o) float x1_##o; float m1_##o;
    REP8_0(D1)
#undef D1
#define FE1(o) { const float* w = W1 + (o)*8; \
    float ya = fa.x*w[0] + fa.y*w[1]; float yb = fa.z*w[2] + fa.w*w[3]; \
    float yc = fb.x*w[4] + fb.y*w[5]; float yd = fb.z*w[6] + fb.w*w[7]; \
    float yy = ((ya+yb)+(yc+yd)) * fold[(o)] + fold[8+(o)]; \
    x1_##o = mishf(yy); }
    REP8_0(FE1)
#undef FE1
#define P1(o) { float a = x1_##o; WMAX32(a); m1_##o = a; }
    REP8_0(P1)
#undef P1

    int nA = __builtin_amdgcn_readfirstlane(__shfl(numv, 0));
    int nB = __builtin_amdgcn_readfirstlane(__shfl(numv, 32));
    const bool skipA = (nA <= 16);   // voxel A rows 16-31 all padding
    const bool skipB = (nB <= 16);   // voxel B rows 16-31 all padding

    // ---- stage fe2 A-operand: concat(x1, m1) split-bf16, row = lane, cols 0-15 ----
#define S1(o) { x2s1[lane*33 + (o)] = splitbf(x1_##o); x2s1[lane*33 + 8 + (o)] = splitbf(m1_##o); }
    REP8_0(S1)
#undef S1

    // ---- preload fe3 kc=0 B-fragments (consumed after fe2 epilogue) ----
    bf16x8 BA[8], BB[8];
    {
        const uint4* bh3 = (const uint4*)w3fh + lane;
        const uint4* bl3 = (const uint4*)w3fl + lane;
        LDB8(BA, bh3, bl3)
    }

    // ---- fe2 on MFMA: 64x32 <- 64x16 (K padded to 32 w/ zero B), 24 MFMAs ----
    f32x4 f2[8];
#pragma unroll
    for (int i = 0; i < 8; i++) f2[i] = (f32x4){0.f,0.f,0.f,0.f};
    {
        { bf16x8 Ah_,Al_; LDA2(x2s1,0,Ah_,Al_) MF3(f2[0],Ah_,Al_,Bw2[0],Bw2[1]) MF3(f2[1],Ah_,Al_,Bw2[2],Bw2[3]) }
        { bf16x8 Ah_,Al_; LDA2(x2s1,1,Ah_,Al_) MF3(f2[2],Ah_,Al_,Bw2[0],Bw2[1]) MF3(f2[3],Ah_,Al_,Bw2[2],Bw2[3]) }
        { bf16x8 Ah_,Al_; LDA2(x2s1,2,Ah_,Al_) MF3(f2[4],Ah_,Al_,Bw2[0],Bw2[1]) MF3(f2[5],Ah_,Al_,Bw2[2],Bw2[3]) }
        { bf16x8 Ah_,Al_; LDA2(x2s1,3,Ah_,Al_) MF3(f2[6],Ah_,Al_,Bw2[0],Bw2[1]) MF3(f2[7],Ah_,Al_,Bw2[2],Bw2[3]) }
    }

    // ---- preload fe3 kc=1 B-fragments (hidden under bn2+pool+staging) ----
    {
        const uint4* bh3 = (const uint4*)w3fh + 256 + lane;
        const uint4* bl3 = (const uint4*)w3fl + 256 + lane;
        LDB8(BB, bh3, bl3)
    }

    // ---- bn2 + mish in C layout ----
    float s2a = fold[16+c0], t2a = fold[48+c0];
    float s2b = fold[32+c0], t2b = fold[64+c0];
#define MSH4(s, SS, TT) { f2[s].x=mishf(f2[s].x*(SS)+(TT)); f2[s].y=mishf(f2[s].y*(SS)+(TT)); \
                          f2[s].z=mishf(f2[s].z*(SS)+(TT)); f2[s].w=mishf(f2[s].w*(SS)+(TT)); }
    MSH4(0,s2a,t2a) MSH4(1,s2b,t2b) MSH4(2,s2a,t2a) MSH4(3,s2b,t2b)
    MSH4(4,s2a,t2a) MSH4(5,s2b,t2b) MSH4(6,s2a,t2a) MSH4(7,s2b,t2b)
#undef MSH4

    // ---- pool over UNMASKED rows (reference pools pre-mask), col-group butterfly ----
#define MX4(V) fmaxf(fmaxf((V).x,(V).y), fmaxf((V).z,(V).w))
    float aggA0 = fmaxf(MX4(f2[0]), MX4(f2[2]));
    float aggA1 = fmaxf(MX4(f2[1]), MX4(f2[3]));
    float aggB0 = fmaxf(MX4(f2[4]), MX4(f2[6]));
    float aggB1 = fmaxf(MX4(f2[5]), MX4(f2[7]));
#undef MX4
#define REDQ(p) p = fmaxf(p, __shfl_xor(p, 16)); p = fmaxf(p, __shfl_xor(p, 32));
    REDQ(aggA0) REDQ(aggA1) REDQ(aggB0) REDQ(aggB1)
#undef REDQ
    // every lane now holds its own channel-c0 pooled values -> no LDS round-trip
    uint sgA0 = splitbf(aggA0), sgA1 = splitbf(aggA1);
    uint sgB0 = splitbf(aggB0), sgB1 = splitbf(aggB1);

    // ---- stage masked x2 into chunk0 (p half) + chunk1 (agg half), [row][ch] ----
#define ST2(mt, NVV, SG0, SG1) { \
    int rt_ = quad*4 + 16*((mt)&1); \
    int gr_ = (quad*4 + 16*(mt))*33; \
    float m0_=(rt_+0<(NVV))?1.f:0.f, m1_=(rt_+1<(NVV))?1.f:0.f; \
    float m2_=(rt_+2<(NVV))?1.f:0.f, m3_=(rt_+3<(NVV))?1.f:0.f; \
    f32x4 a_ = f2[(mt)*2], b_ = f2[(mt)*2+1]; \
    x2s[gr_    + c0] = splitbf(a_.x*m0_);  x2s[gr_    + c0+16] = splitbf(b_.x*m0_); \
    x2s[gr_+33 + c0] = splitbf(a_.y*m1_);  x2s[gr_+33 + c0+16] = splitbf(b_.y*m1_); \
    x2s[gr_+66 + c0] = splitbf(a_.z*m2_);  x2s[gr_+66 + c0+16] = splitbf(b_.z*m2_); \
    x2s[gr_+99 + c0] = splitbf(a_.w*m3_);  x2s[gr_+99 + c0+16] = splitbf(b_.w*m3_); \
    x2s1[gr_    + c0] = (m0_!=0.f)?(SG0):0u;  x2s1[gr_    + c0+16] = (m0_!=0.f)?(SG1):0u; \
    x2s1[gr_+33 + c0] = (m1_!=0.f)?(SG0):0u;  x2s1[gr_+33 + c0+16] = (m1_!=0.f)?(SG1):0u; \
    x2s1[gr_+66 + c0] = (m2_!=0.f)?(SG0):0u;  x2s1[gr_+66 + c0+16] = (m2_!=0.f)?(SG1):0u; \
    x2s1[gr_+99 + c0] = (m3_!=0.f)?(SG0):0u;  x2s1[gr_+99 + c0+16] = (m3_!=0.f)?(SG1):0u; }
    ST2(0, nA, sgA0, sgA1)
    ST2(2, nB, sgB0, sgB1)
    if (!skipA) { ST2(1, nA, sgA0, sgA1) }
    if (!skipB) { ST2(3, nB, sgB0, sgB1) }
#undef ST2

    // ---- fe3: up to 96 MFMAs over K=64 (two 32-K sets), dead tiles skipped ----
    f32x4 e[16];
#define EIN(i) e[i] = (f32x4){0.f,0.f,0.f,0.f};
    REP16_0(EIN)
#undef EIN
    DOSETA(x2s,  BA, e, skipA, skipB)
    DOSETA(x2s1, BB, e, skipA, skipB)

    // ---- preload fe4 kc=0 B-fragments (hidden under POST block 1) ----
    {
        const uint4* bh4 = (const uint4*)w4fh + lane;
        const uint4* bl4 = (const uint4*)w4fl + lane;
        LDB8(BA, bh4, bl4)
    }

    // ---- fe3 epilogue (bn+mish+split, C-layout) interleaved with fe4 MFMA ----
    uint* x3st = x2s1;   // agg chunk reused as x3 staging
    f32x4 d[16];
#define DIN(i) d[i] = (f32x4){0.f,0.f,0.f,0.f};
    REP16_0(DIN)
#undef DIN

#define POST(TI, mt, nt) { \
    float s_ = fold[80 + c0 + 16*(nt)], tb_ = fold[144 + c0 + 16*(nt)]; \
    int col_ = c0 + 16*((nt)&1); \
    int rowb_ = quad*4 + 16*(mt); \
    x3st[(rowb_+0)*33 + col_] = splitbf(mishf(e[TI].x * s_ + tb_)); \
    x3st[(rowb_+1)*33 + col_] = splitbf(mishf(e[TI].y * s_ + tb_)); \
    x3st[(rowb_+2)*33 + col_] = splitbf(mishf(e[TI].z * s_ + tb_)); \
    x3st[(rowb_+3)*33 + col_] = splitbf(mishf(e[TI].w * s_ + tb_)); }

    { // output chunk 0: fe3 outputs 0..31 (nt 0,1)
        POST(0,0,0)  POST(1,0,1)
        POST(8,2,0)  POST(9,2,1)
        if (!skipA) { POST(4,1,0)  POST(5,1,1) }
        if (!skipB) { POST(12,3,0) POST(13,3,1) }
        DOSETA(x3st, BA, d, skipA, skipB)
    }
    // preload fe4 kc=1 B-fragments (hidden under POST block 2)
    {
        const uint4* bh4 = (const uint4*)w4fh + 256 + lane;
        const uint4* bl4 = (const uint4*)w4fl + 256 + lane;
        LDB8(BB, bh4, bl4)
    }
    { // output chunk 1: fe3 outputs 32..63 (nt 2,3)
        POST(2,0,2)  POST(3,0,3)
        POST(10,2,2) POST(11,2,3)
        if (!skipA) { POST(6,1,2)  POST(7,1,3) }
        if (!skipB) { POST(14,3,2) POST(15,3,3) }
        DOSETA(x3st, BB, d, skipA, skipB)
    }
#undef POST

    // ---- bn4 + mish + residual + pool in C layout ----
    float s0f = fold[208+c0],    t0f = fold[272+c0];
    float s1f = fold[208+16+c0], t1f = fold[272+16+c0];
    float s2f = fold[208+32+c0], t2f = fold[272+32+c0];
    float s3f = fold[208+48+c0], t3f = fold[272+48+c0];
    // Skipped tiles' rows would contribute exactly 0 to the pool -> seed 0.
    float piA = skipA ? 0.f : -3.4e38f;
    float piB = skipB ? 0.f : -3.4e38f;
    float pA0=piA, pA1=piA, pA2=piA, pA3=piA;
    float pB0=piB, pB1=piB, pB2=piB, pB3=piB;

#define RECON(u) (__uint_as_float((u)<<16) + __uint_as_float((u) & 0xFFFF0000u))
#define FTP(D, mt, nt, SS, TT, PV) { \
    int nv = ((mt) >> 1) ? nB : nA; \
    int rf = quad*4 + 16*(mt); \
    int rt = quad*4 + 16*((mt)&1); \
    int cb = c0 + 16*(nt); \
    float m0=(rt+0<nv)?1.f:0.f, m1=(rt+1<nv)?1.f:0.f, m2=(rt+2<nv)?1.f:0.f, m3=(rt+3<nv)?1.f:0.f; \
    uint ua_ = x2s[(rf+0)*33 + cb], ub_ = x2s[(rf+1)*33 + cb]; \
    uint uc_ = x2s[(rf+2)*33 + cb], ud_ = x2s[(rf+3)*33 + cb]; \
    float y0 = mishf(D.x*SS + TT)*m0 + RECON(ua_); \
    float y1 = mishf(D.y*SS + TT)*m1 + RECON(ub_); \
    float y2 = mishf(D.z*SS + TT)*m2 + RECON(uc_); \
    float y3 = mishf(D.w*SS + TT)*m3 + RECON(ud_); \
    PV = fmaxf(PV, fmaxf(fmaxf(y0,y1), fmaxf(y2,y3))); }

#define FTA(D, mt, nt, SS, TT, AG, PV) { \
    int nv = ((mt) >> 1) ? nB : nA; \
    int rt = quad*4 + 16*((mt)&1); \
    float m0=(rt+0<nv)?1.f:0.f, m1=(rt+1<nv)?1.f:0.f, m2=(rt+2<nv)?1.f:0.f, m3=(rt+3<nv)?1.f:0.f; \
    float y0 = (mishf(D.x*SS + TT) + AG)*m0; \
    float y1 = (mishf(D.y*SS + TT) + AG)*m1; \
    float y2 = (mishf(D.z*SS + TT) + AG)*m2; \
    float y3 = (mishf(D.w*SS + TT) + AG)*m3; \
    PV = fmaxf(PV, fmaxf(fmaxf(y0,y1), fmaxf(y2,y3))); }

    FTP(d[0], 0, 0, s0f, t0f, pA0)  FTP(d[1], 0, 1, s1f, t1f, pA1)
    FTA(d[2], 0, 2, s2f, t2f, aggA0, pA2)  FTA(d[3], 0, 3, s3f, t3f, aggA1, pA3)
    if (!skipA) {
        FTP(d[4], 1, 0, s0f, t0f, pA0)  FTP(d[5], 1, 1, s1f, t1f, pA1)
        FTA(d[6], 1, 2, s2f, t2f, aggA0, pA2)  FTA(d[7], 1, 3, s3f, t3f, aggA1, pA3)
    }
    FTP(d[8], 2, 0, s0f, t0f, pB0)  FTP(d[9], 2, 1, s1f, t1f, pB1)
    FTA(d[10], 2, 2, s2f, t2f, aggB0, pB2)  FTA(d[11], 2, 3, s3f, t3f, aggB1, pB3)
    if (!skipB) {
        FTP(d[12], 3, 0, s0f, t0f, pB0)  FTP(d[13], 3, 1, s1f, t1f, pB1)
        FTA(d[14], 3, 2, s2f, t2f, aggB0, pB2)  FTA(d[15], 3, 3, s3f, t3f, aggB1, pB3)
    }
#undef FTP
#undef FTA
#undef RECON

#define RED(p) p = fmaxf(p, __shfl_xor(p, 16)); p = fmaxf(p, __shfl_xor(p, 32));
    RED(pA0) RED(pA1) RED(pA2) RED(pA3) RED(pB0) RED(pB1) RED(pB2) RED(pB3)
#undef RED

    if (quad == 0) {
        float* vwA = voxelwise + vA*64;
        vwA[c0] = pA0; vwA[c0+16] = pA1; vwA[c0+32] = pA2; vwA[c0+48] = pA3;
        float* vwB = voxelwise + (vA+1)*64;
        vwB[c0] = pB0; vwB[c0+16] = pB1; vwB[c0+32] = pB2; vwB[c0+48] = pB3;
    }

    if (t == 0) {
        int cell = coors[v*2] * BEVW + coors[v*2+1];
        int pos = atomicAdd(&cnt[cell], 1);
        if (pos < 16) list[cell*16 + pos] = v;
        if (pos == 0) { int k = atomicAdd(nact, 1); act[k] = cell; }
    }
}

// ---------------- BFE front: 1 wave = 1 cell; records idx[cell]=aidx+1 ----------------
__global__ __launch_bounds__(256) void bfe_front(
    const int* __restrict__ nact, const int* __restrict__ act,
    const int* __restrict__ cnt, const int* __restrict__ list,
    const float* __restrict__ voxelwise,
    const float* __restrict__ W1g, const float* __restrict__ W2g,
    const float* __restrict__ fold, float* __restrict__ x17g,
    int* __restrict__ idx)
{
    int n_act = *nact;
    int aidx = blockIdx.x * 4 + (threadIdx.x >> 6);
    if (aidx >= n_act) return;

    int lane = threadIdx.x & 63;
    int g = lane >> 2, ii = lane & 3;
    int cell = act[aidx];
    int numv = min(cnt[cell], 16);
    if (lane == 0) idx[cell] = aidx + 1;

    int myidx = (lane < numv) ? list[cell*16 + lane] : (0x40000000 + lane);
    int rank = 0;
    for (int j = 0; j < numv; j++) { int vj = __shfl(myidx, j); rank += (vj < myidx) ? 1 : 0; }
    if (lane >= numv) rank = lane;
    int sorted = __builtin_amdgcn_ds_permute(rank << 2, myidx);

#define YD(q) float y_##q = 0.f;
    REP16_0(YD)
#undef YD
    for (int p = 0; p < numv; p++) {
        int sv = __shfl(sorted, p);
        float val = voxelwise[sv*64 + lane];
        const float* w = W1g + g*256 + p;
#define BF1(q) y_##q += val * w[(q)*16];
        REP16_0(BF1)
#undef BF1
    }
#define BN1(q) { float yy = y_##q * fold[592 + g*16 + (q)] + fold[848 + g*16 + (q)]; \
    yy = mishf(yy); y_##q = ((q) < numv) ? yy : 0.f; }
    REP16_0(BN1)
#undef BN1

    float z0 = 0.f, z1 = 0.f;
#define BF2(p) z0 += y_##p * W2g[g*32 + (p)]; z1 += y_##p * W2g[g*32 + 16 + (p)];
    REP16_0(BF2)
#undef BF2
    z0 = mishf(z0 * fold[1104 + g*2 + 0] + fold[1136 + g*2 + 0]);
    z1 = mishf(z1 * fold[1104 + g*2 + 1] + fold[1136 + g*2 + 1]);

    int k0 = ii*32 + g*2;
    *(float2*)(x17g + aidx*128 + k0) = make_float2(z0, z1);
}

// ---------------- bfe3 fused: x19 compactly back into x17g ----------------
__global__ __launch_bounds__(512, 4) void bfe3_fused(
    const int* __restrict__ nactp,
    const float* __restrict__ W3, const float* __restrict__ fold,
    float* __restrict__ x17g)
{
    __shared__ float XL[64*128];
    int tid = threadIdx.x;
    int n_act = *nactp;
    int cb = blockIdx.x * 64;

    for (int i = tid; i < 64*32; i += 512) {
        int c = i >> 5, kc = i & 31;
        float4 val = (cb + c < n_act) ? ((const float4*)x17g)[(size_t)(cb+c)*32 + kc]
                                      : make_float4(0.f,0.f,0.f,0.f);
        ((float4*)XL)[c*32 + (kc ^ (c & 31))] = val;
    }
    __syncthreads();

    int wv = __builtin_amdgcn_readfirstlane(tid >> 6);
    int c  = tid & 63;
    int ob = wv * 16;
    int cswz = c & 31;
    const float4* xrow = (const float4*)XL + c*32;
    const float4* W4p = (const float4*)W3;

#define DECLB(q) f32x2 ap_##q = {0.f, 0.f};
#define ACCB(q) { const f32x2* wp_ = (const f32x2*)(W4p + (ob+(q))*32 + kc); \
    ap_##q += xv01 * wp_[0]; ap_##q += xv23 * wp_[1]; }
#define ACTB(q) float a_##q; { float yy = (ap_##q.x + ap_##q.y) * fold[336+ob+(q)] + fold[464+ob+(q)]; a_##q = mishf(yy); }
    {
        REP16_0(DECLB)
        for (int kc = 0; kc < 32; kc++) {
            float4 xv = xrow[kc ^ cswz];
            f32x2 xv01 = {xv.x, xv.y}, xv23 = {xv.z, xv.w};
            REP16_0(ACCB)
        }
        REP16_0(ACTB)
        __syncthreads();
        ((float4*)XL)[c*32 + ((wv*4 + 0) ^ cswz)] = make_float4(a_0,  a_1,  a_2,  a_3);
        ((float4*)XL)[c*32 + ((wv*4 + 1) ^ cswz)] = make_float4(a_4,  a_5,  a_6,  a_7);
        ((float4*)XL)[c*32 + ((wv*4 + 2) ^ cswz)] = make_float4(a_8,  a_9,  a_10, a_11);
        ((float4*)XL)[c*32 + ((wv*4 + 3) ^ cswz)] = make_float4(a_12, a_13, a_14, a_15);
    }
    __syncthreads();

    {
        const float4* yrow = (const float4*)XL + c*32;
        REP16_0(DECLB)
        for (int kc = 0; kc < 32; kc++) {
            float4 xv = yrow[kc ^ cswz];
            f32x2 xv01 = {xv.x, xv.y}, xv23 = {xv.z, xv.w};
            REP16_0(ACCB)
        }
        REP16_0(ACTB)
        float4* dst = (float4*)(x17g + (size_t)(cb + c)*128 + ob);
        dst[0] = make_float4(a_0,  a_1,  a_2,  a_3);
        dst[1] = make_float4(a_4,  a_5,  a_6,  a_7);
        dst[2] = make_float4(a_8,  a_9,  a_10, a_11);
        dst[3] = make_float4(a_12, a_13, a_14, a_15);
    }
#undef DECLB
#undef ACCB
#undef ACTB
}

// ---------------- bev_write: tiled transpose-scatter (replaces out memset) ----------------
__global__ __launch_bounds__(512, 2) void bev_write(
    const int* __restrict__ idx, const float* __restrict__ x19c,
    float* __restrict__ out)
{
    __shared__ float XT[128*65];
    int bid = blockIdx.x;
    int cx = bid % BEVW;
    int cy0 = (bid / BEVW) << 6;
    int tid = threadIdx.x;

    int cell_l = tid >> 3;
    int chq = (tid & 7) << 4;
    int cy = cy0 + cell_l;
    float4 v0 = make_float4(0.f,0.f,0.f,0.f), v1 = v0, v2 = v0, v3 = v0;
    if (cy < BEVH) {
        int ai = idx[cy*BEVW + cx] - 1;
        if (ai >= 0) {
            const float4* src = (const float4*)(x19c + (size_t)ai*128 + chq);
            v0 = src[0]; v1 = src[1]; v2 = src[2]; v3 = src[3];
        }
    }
    float* d = XT + chq*65 + cell_l;
    d[0*65]=v0.x;  d[1*65]=v0.y;  d[2*65]=v0.z;  d[3*65]=v0.w;
    d[4*65]=v1.x;  d[5*65]=v1.y;  d[6*65]=v1.z;  d[7*65]=v1.w;
    d[8*65]=v2.x;  d[9*65]=v2.y;  d[10*65]=v2.z; d[11*65]=v2.w;
    d[12*65]=v3.x; d[13*65]=v3.y; d[14*65]=v3.z; d[15*65]=v3.w;
    __syncthreads();

    int wv2 = tid >> 6, lane = tid & 63;
    int cyw = cy0 + lane;
    if (cyw < BEVH) {
        float* op = out + cx*BEVH + cyw;
#pragma unroll
        for (int k = 0; k < 16; k++) {
            int c = (wv2 << 4) + k;
            op[(size_t)c*NCELL] = XT[c*65 + lane];
        }
    }
}

extern "C" void kernel_launch(void* const* d_in, const int* in_sizes, int n_in,
                              void* d_out, int out_size, void* d_ws, size_t ws_size,
                              hipStream_t stream) {
    const float* features = (const float*)d_in[0];
    const int*   coors    = (const int*)d_in[1];
    const int*   num_vox  = (const int*)d_in[2];
    const float* vfe1_W   = (const float*)d_in[3];
    const float* vfe1_bn  = (const float*)d_in[4];
    const float* vfe2_W   = (const float*)d_in[5];
    const float* vfe2_bn  = (const float*)d_in[6];
    const float* vfe3_W   = (const float*)d_in[7];
    const float* vfe3_bn  = (const float*)d_in[8];
    const float* vfe4_W   = (const float*)d_in[9];
    const float* vfe4_bn  = (const float*)d_in[10];
    const float* bfe1_W   = (const float*)d_in[11];
    const float* bfe1_bn  = (const float*)d_in[12];
    const float* bfe2_W   = (const float*)d_in[13];
    const float* bfe2_bn  = (const float*)d_in[14];
    const float* bfe3_W   = (const float*)d_in[15];
    const float* bfe3_bn  = (const float*)d_in[16];
    float* out = (float*)d_out;

    char* ws = (char*)d_ws;
    int*    nact      = (int*)ws;                       // zeroed
    int*    cnt       = (int*)(ws + 256);               // zeroed
    int*    idx       = (int*)(ws + 857344);            // zeroed (aidx+1 encoding)
    int*    list      = (int*)(ws + 1714432);
    float*  voxelwise = (float*)(ws + 15427840);
    int*    act       = (int*)(ws + 25667840);
    float*  x17g      = (float*)(ws + 25827840);
    float*  fold      = (float*)(ws + 46307840);
    ushort* w4fh      = (ushort*)(ws + 46312512);
    ushort* w4fl      = (ushort*)(ws + 46320704);
    ushort* w3fh      = (ushort*)(ws + 46328896);
    ushort* w3fl      = (ushort*)(ws + 46337088);
    ushort* w2fh      = (ushort*)(ws + 46345280);
    ushort* w2fl      = (ushort*)(ws + 46347328);

    (void)hipMemsetAsync(ws, 0, 1714432, stream);   // nact + cnt + idx in one shot

    setup_kernel<<<1, 256, 0, stream>>>(vfe1_bn, vfe2_bn, vfe3_bn, vfe4_bn,
                                        bfe1_bn, bfe2_bn, bfe3_bn, vfe4_W, vfe3_W, vfe2_W,
                                        fold, w4fh, w4fl, w3fh, w3fl, w2fh, w2fl);
    vfe_kernel<<<NVOX/2, 64, 0, stream>>>(features, coors, num_vox,
                                          vfe1_W, w2fh, w2fl, w3fh, w3fl, w4fh, w4fl, fold,
                                          voxelwise, cnt, list, nact, act);
    bfe_front<<<NVOX/4, 256, 0, stream>>>(nact, act, cnt, list, voxelwise,
                                          bfe1_W, bfe2_W, fold, x17g, idx);
    bfe3_fused<<<(NVOX+63)/64, 512, 0, stream>>>(nact, bfe3_W, fold, x17g);
    bev_write<<<BEVW*8, 512, 0, stream>>>(idx, x17g, out);
}